// Round 6
// baseline (308.953 us; speedup 1.0000x reference)
//
#include <hip/hip_runtime.h>
#include <math.h>

#define SA 8      /* segments for kA */
#define SEGE 8    /* segments for kE (keeps R3 S-grouping exactly) */
#define SEGM 32   /* segments for kM1 (pure parallelism, numerics-neutral) */
#define NB 4096
#define TAA 512   /* kA threads */
#define HS 256    /* kA histogram-scan owner threads */
#define TE 512    /* kE threads */
#define TBB 1024  /* kH / kM1 threads */
#define SCT 256   /* scan threads (R3-proven chunk structure) */
#define CH (NB / SCT) /* 16 */
#define CAPSEG 512
#define GTOT (SA * CAPSEG) /* 4096 */
#define MAXM1 16
#define GB1 16384 /* gathered crossing-bin cap per mode-1 row */
#define SUBC 512  /* sub-bin cap */
#define EQC 64
#define FXS 1099511627776.0f /* 2^40 */
#define FXI (1.0f / 1099511627776.0f)

typedef unsigned u32;
typedef unsigned long long u64;

struct ScanSh {
  u32 axc[SCT]; float axe[SCT];
  u32 sufc[SCT]; float sufe[SCT];
  int cbin[SCT]; u32 cca[SCT]; float cea[SCT];
  int fbin[SCT]; u32 fca[SCT]; float fea[SCT];
};

__device__ __forceinline__ u32 f2key(float f) {
  u32 u = __float_as_uint(f);
  return u ^ ((u >> 31) ? 0xFFFFFFFFu : 0x80000000u);
}
__device__ __forceinline__ int is_mode0(int k, int V) {
  return (k >= 1 && k <= 256 && k < V);
}

// Deterministic slot = prefix count of mode-1 rows < row (parallel ballot-sum).
__device__ int m1_slot(const int* topks, int row, int V, int tid, int* red) {
  if (tid < 128) {
    int c = 0;
    for (int r = tid; r < row; r += 128) c += !is_mode0(topks[r], V);
    red[tid] = c;
  }
  __syncthreads();
  for (int s = 64; s > 0; s >>= 1) {
    if (tid < s) red[tid] += red[tid + s];
    __syncthreads();
  }
  return red[0];
}

__device__ __forceinline__ float row_max(const float* maxpart, int row) {
  float mm = maxpart[row * SA];
  for (int j = 1; j < SA; ++j) mm = fmaxf(mm, maxpart[row * SA + j]);
  return mm;
}

// R3-proven level-0 crossing scan, 256-owner structure.
__device__ void scan_level(const u32* cnt, const u64* e0, ScanSh* ax,
                           u32* sprefix, int* scnt_above, float* sexp_above,
                           float target, int tid) {
  if (tid < SCT) {
    u32 cc = 0; float ce = 0.f; const int base = tid * CH;
    for (int j = 0; j < CH; ++j) { cc += cnt[base + j]; ce += (float)e0[base + j] * FXI; }
    ax->axc[tid] = cc; ax->axe[tid] = ce;
  }
  __syncthreads();
  if (tid == 0) {
    u32 rc = 0; float re = 0.f;
    for (int c = SCT - 1; c >= 0; --c) {
      ax->sufc[c] = rc; ax->sufe[c] = re;
      rc += ax->axc[c]; re += ax->axe[c];
    }
  }
  __syncthreads();
  if (tid < SCT) {
    const int base = tid * CH;
    u32 rc = ax->sufc[tid]; float re = ax->sufe[tid];
    int best = -1; u32 bca = 0; float bea = 0.f;
    int fb = -1; u32 ffca = 0; float ffea = 0.f;
    for (int b = base + CH - 1; b >= base; --b) {
      u32 c = cnt[b]; float ebv = (float)e0[b] * FXI;
      bool cross = (c > 0) && ((re + ebv) >= target);
      if (cross && best < 0) { best = b; bca = rc; bea = re; }
      if (c > 0) { fb = b; ffca = rc; ffea = re; }
      rc += c; re += ebv;
    }
    ax->cbin[tid] = best; ax->cca[tid] = bca; ax->cea[tid] = bea;
    ax->fbin[tid] = fb; ax->fca[tid] = ffca; ax->fea[tid] = ffea;
  }
  __syncthreads();
  if (tid == 0) {
    int bsel = -1; u32 ca = 0; float ea = 0.f;
    for (int c = 0; c < SCT; ++c) {
      int b = ax->cbin[c];
      if (b > bsel) { bsel = b; ca = ax->cca[c]; ea = ax->cea[c]; }
    }
    if (bsel < 0) {
      for (int c = 0; c < SCT; ++c) {
        int b = ax->fbin[c];
        if (b >= 0 && (bsel < 0 || b < bsel)) { bsel = b; ca = ax->fca[c]; ea = ax->fea[c]; }
      }
    }
    if (bsel < 0) bsel = 0;
    *sprefix = (u32)bsel;
    *scnt_above = (int)ca;
    *sexp_above = ea;
  }
  __syncthreads();
}

// kA: RAW-KEY version. f2key(v/t) is monotone in v (t>0), so histogram,
// threshold bin, and candidate predicate all run on raw f2key(v) — no divides
// in the hot loops. Selected candidate superset = same top-set; stored values
// are exact v/t (computed only on acceptance). Seg max: max(v/t) == max(v)/t
// bitwise (monotone division; same argmax element). Also zero-fills the
// mode-1 accumulators (replaces the hipMemsetAsync dispatch).
__global__ __launch_bounds__(TAA) void kA(const float* __restrict__ logits,
                                          const float* __restrict__ temps,
                                          const int* __restrict__ topks,
                                          float* __restrict__ maxpart,
                                          u32* __restrict__ scnt,
                                          float* __restrict__ candv,
                                          int* __restrict__ candi,
                                          u32* __restrict__ zp, size_t zwords,
                                          int V) {
  const int row = blockIdx.x, seg = blockIdx.y, tid = threadIdx.x;
  __shared__ u32 cnt[NB];
  __shared__ float sm[TAA];
  __shared__ u32 cs[HS];
  __shared__ int bb[HS];
  __shared__ int lcnt;
  __shared__ u32 sT;
  {
    const size_t gid = ((size_t)blockIdx.y * gridDim.x + blockIdx.x) * TAA + tid;
    const size_t stride = (size_t)gridDim.x * gridDim.y * TAA;
    for (size_t i = gid; i < zwords; i += stride) zp[i] = 0;
  }
  const int k = topks[row];
  const int m0 = is_mode0(k, V);
  const float t = temps[row];
  const float* lr = logits + (size_t)row * V;
  const float4* l4 = (const float4*)lr;
  const int n4 = V >> 2;
  const int q0 = (int)((long long)seg * n4 / SA);
  const int q1 = (int)((long long)(seg + 1) * n4 / SA);
  float rmx = -INFINITY;  // raw-domain max
  if (m0) {
    for (int i = tid; i < NB; i += TAA) cnt[i] = 0;
    if (tid == 0) lcnt = 0;
    __syncthreads();
    for (int i = q0 + tid; i < q1; i += TAA) {
      float4 v = l4[i];
      rmx = fmaxf(rmx, fmaxf(fmaxf(v.x, v.y), fmaxf(v.z, v.w)));
      atomicAdd(&cnt[f2key(v.x) >> 20], 1u);
      atomicAdd(&cnt[f2key(v.y) >> 20], 1u);
      atomicAdd(&cnt[f2key(v.z) >> 20], 1u);
      atomicAdd(&cnt[f2key(v.w) >> 20], 1u);
    }
    if (seg == SA - 1)
      for (int i = (n4 << 2) + tid; i < V; i += TAA) {
        float x = lr[i];
        rmx = fmaxf(rmx, x);
        atomicAdd(&cnt[f2key(x) >> 20], 1u);
      }
  } else {
    for (int i = q0 + tid; i < q1; i += TAA) {
      float4 v = l4[i];
      rmx = fmaxf(rmx, fmaxf(fmaxf(v.x, v.y), fmaxf(v.z, v.w)));
    }
    if (seg == SA - 1)
      for (int i = (n4 << 2) + tid; i < V; i += TAA) rmx = fmaxf(rmx, lr[i]);
  }
  sm[tid] = rmx;
  __syncthreads();
  for (int s = TAA >> 1; s > 0; s >>= 1) {
    if (tid < s) sm[tid] = fmaxf(sm[tid], sm[tid + s]);
    __syncthreads();
  }
  if (tid == 0) maxpart[row * SA + seg] = sm[0] / t;  // exact: max(v)/t == max(v/t)
  if (!m0) return;
  if (tid < HS) {
    u32 cc = 0; const int base = tid * (NB / HS);
    for (int j = 0; j < NB / HS; ++j) cc += cnt[base + j];
    cs[tid] = cc;
  }
  __syncthreads();
  if (tid == 0) {
    u32 rc = 0;
    for (int c = HS - 1; c >= 0; --c) { u32 tmp = cs[c]; cs[c] = rc; rc += tmp; }
  }
  __syncthreads();
  const int kk = (k > 256) ? 256 : k;
  if (tid < HS) {
    const int base = tid * (NB / HS);
    u32 rc = cs[tid]; int best = -1;
    for (int b = base + NB / HS - 1; b >= base; --b) {
      u32 c = cnt[b];
      if (c && best < 0 && (int)(rc + c) >= kk) best = b;
      rc += c;
    }
    bb[tid] = best;
  }
  __syncthreads();
  if (tid == 0) {
    int bsel = -1;
    for (int c = 0; c < HS; ++c) if (bb[c] > bsel) bsel = bb[c];
    if (bsel < 0) { for (int b = 0; b < NB; ++b) if (cnt[b]) { bsel = b; break; } }
    if (bsel < 0) bsel = 0;
    sT = ((u32)bsel) << 20;
  }
  __syncthreads();
  const u32 T = sT;  // raw-domain threshold
  const size_t cbase = ((size_t)row * SA + seg) * CAPSEG;
  for (int i = q0 + tid; i < q1; i += TAA) {
    float4 v = l4[i];
    float vs[4] = {v.x, v.y, v.z, v.w};
#pragma unroll
    for (int j = 0; j < 4; ++j) {
      if (f2key(vs[j]) >= T) {
        int s = atomicAdd(&lcnt, 1);
        if (s < CAPSEG) { candv[cbase + s] = vs[j] / t; candi[cbase + s] = i * 4 + j; }
      }
    }
  }
  if (seg == SA - 1)
    for (int i = (n4 << 2) + tid; i < V; i += TAA) {
      float x = lr[i];
      if (f2key(x) >= T) {
        int s = atomicAdd(&lcnt, 1);
        if (s < CAPSEG) { candv[cbase + s] = x / t; candi[cbase + s] = i; }
      }
    }
  __syncthreads();
  if (tid == 0) { int n = lcnt; if (n > CAPSEG) n = CAPSEG; scnt[row * SA + seg] = (u32)n; }
}

// kE: mode-1 rows, seg-parallel level-0 12-bit count + fixed-point esum + S
// partials into per-slot global accumulators (zeroed by kA). R3-proven,
// numerics unchanged (SEGE=8 keeps S grouping identical).
__global__ __launch_bounds__(TE) void kE(const float* __restrict__ logits,
                                         const float* __restrict__ temps,
                                         const int* __restrict__ topks,
                                         const float* __restrict__ maxpart,
                                         float* __restrict__ Sparts,
                                         u32* __restrict__ m1c0,
                                         u64* __restrict__ m1e0, int V) {
  const int row = blockIdx.x, seg = blockIdx.y, tid = threadIdx.x;
  const int k = topks[row];
  if (is_mode0(k, V)) return;
  __shared__ int red[128];
  const int slot = m1_slot(topks, row, V, tid, red);
  if (slot >= MAXM1) return;
  __shared__ u32 c0[NB];
  __shared__ u64 e0[NB];
  __shared__ float ss[TE];
  for (int i = tid; i < NB; i += TE) { c0[i] = 0; e0[i] = 0ull; }
  __syncthreads();
  const float t = temps[row];
  const float m = row_max(maxpart, row);
  const float* lr = logits + (size_t)row * V;
  const float4* l4 = (const float4*)lr;
  const int n4 = V >> 2;
  const int q0 = (int)((long long)seg * n4 / SEGE);
  const int q1 = (int)((long long)(seg + 1) * n4 / SEGE);
  float ls = 0.f;
  for (int i = q0 + tid; i < q1; i += TE) {
    float4 v = l4[i];
    float xs[4] = {v.x / t, v.y / t, v.z / t, v.w / t};
#pragma unroll
    for (int j = 0; j < 4; ++j) {
      float e = expf(xs[j] - m);
      ls += e;
      u32 b = f2key(xs[j]) >> 20;
      atomicAdd(&c0[b], 1u);
      u64 fx = (u64)(e * FXS);
      if (fx) atomicAdd(&e0[b], fx);
    }
  }
  if (seg == SEGE - 1)
    for (int i = (n4 << 2) + tid; i < V; i += TE) {
      float x = lr[i] / t;
      float e = expf(x - m);
      ls += e;
      u32 b = f2key(x) >> 20;
      atomicAdd(&c0[b], 1u);
      u64 fx = (u64)(e * FXS);
      if (fx) atomicAdd(&e0[b], fx);
    }
  ss[tid] = ls;
  __syncthreads();
  for (int s = TE >> 1; s > 0; s >>= 1) {
    if (tid < s) ss[tid] += ss[tid + s];
    __syncthreads();
  }
  if (tid == 0) Sparts[slot * SEGE + seg] = ss[0];
  for (int b = tid; b < NB; b += TE) {
    u32 c = c0[b]; if (c) atomicAdd(&m1c0[(size_t)slot * NB + b], c);
    u64 e = e0[b]; if (e) atomicAdd(&m1e0[(size_t)slot * NB + b], e);
  }
}

// kM1: mode-1 finish, seg-parallel (SEGM=32 for 4x the R3 parallelism; pure
// grouping change — race is exact max, gather set unchanged). Each seg block:
// redundant LDS scan (deterministic), gather its segment's crossing-bin elems
// (packed u64 atomicExch, small volume), race its segment's sure-kept
// (bin>pfx; /Z2 dropped — constant factor). Last arriver (rdone) does the
// sub-scan/sort/replay + boundary race on the gathered set and writes out.
__global__ __launch_bounds__(TBB) void kM1(const float* __restrict__ logits,
                                           const float* __restrict__ temps,
                                           const int* __restrict__ topks,
                                           const float* __restrict__ topps,
                                           const float* __restrict__ noise,
                                           const float* __restrict__ maxpart,
                                           const float* __restrict__ Sparts,
                                           const u32* __restrict__ m1c0,
                                           const u64* __restrict__ m1e0,
                                           u64* __restrict__ g1p,
                                           u32* __restrict__ gcnt,
                                           u64* __restrict__ rpack,
                                           u32* __restrict__ rdone,
                                           int* __restrict__ out, int V) {
  const int row = blockIdx.x, seg = blockIdx.y, tid = threadIdx.x;
  const int k = topks[row];
  if (is_mode0(k, V)) return;
  __shared__ int red[128];
  const int slot = m1_slot(topks, row, V, tid, red);
  if (slot >= MAXM1) return;

  __shared__ u32 cnt[NB];      // 16KB
  __shared__ u64 e0[NB];       // 32KB
  __shared__ ScanSh ax;        // 10KB
  __shared__ u32 spfx; __shared__ int sca; __shared__ float sea;
  __shared__ float rr[TBB]; __shared__ int ri[TBB];  // 8KB
  for (int i = tid; i < NB; i += TBB) {
    cnt[i] = m1c0[(size_t)slot * NB + i];
    e0[i] = m1e0[(size_t)slot * NB + i];
  }
  __syncthreads();
  float S = 0.f;
  for (int j = 0; j < SEGE; ++j) S += Sparts[slot * SEGE + j];
  const float target = topps[row] * S;
  scan_level(cnt, e0, &ax, &spfx, &sca, &sea, target, tid);
  const u32 pfx = spfx;

  const float t = temps[row];
  const float m = row_max(maxpart, row);
  const float* lr = logits + (size_t)row * V;
  const float* ur = noise + (size_t)row * V;
  const float4* l4 = (const float4*)lr;
  const float4* u4 = (const float4*)ur;
  const int n4 = V >> 2;
  const int q0 = (int)((long long)seg * n4 / SEGM);
  const int q1 = (int)((long long)(seg + 1) * n4 / SEGM);
  const size_t gbase = (size_t)slot * GB1;

  float best = -1.f; int bidx = 0x7FFFFFFF;
  for (int i = q0 + tid; i < q1; i += TBB) {
    float4 xv = l4[i];
    float4 uv = u4[i];
    float xs[4] = {xv.x / t, xv.y / t, xv.z / t, xv.w / t};
    float us[4] = {uv.x, uv.y, uv.z, uv.w};
#pragma unroll
    for (int j = 0; j < 4; ++j) {
      u32 key = f2key(xs[j]);
      u32 bin = key >> 20;
      int idx = i * 4 + j;
      if (bin == pfx) {
        u32 s2 = atomicAdd(&gcnt[slot], 1u);
        if (s2 < GB1)
          atomicExch(&g1p[gbase + s2],
                     ((u64)__float_as_uint(xs[j]) << 32) | (u64)(u32)idx);
      } else if (bin > pfx) {
        float q = fmaxf(-logf(us[j]), 1e-10f);
        float rt = expf(xs[j] - m) / q;
        if (rt > best || (rt == best && idx < bidx)) { best = rt; bidx = idx; }
      }
    }
  }
  if (seg == SEGM - 1)
    for (int i = (n4 << 2) + tid; i < V; i += TBB) {
      float x = lr[i] / t;
      u32 key = f2key(x);
      u32 bin = key >> 20;
      if (bin == pfx) {
        u32 s2 = atomicAdd(&gcnt[slot], 1u);
        if (s2 < GB1)
          atomicExch(&g1p[gbase + s2],
                     ((u64)__float_as_uint(x) << 32) | (u64)(u32)i);
      } else if (bin > pfx) {
        float q = fmaxf(-logf(ur[i]), 1e-10f);
        float rt = expf(x - m) / q;
        if (rt > best || (rt == best && i < bidx)) { best = rt; bidx = i; }
      }
    }
  rr[tid] = best; ri[tid] = bidx;
  __syncthreads();
  for (int s = TBB >> 1; s > 0; s >>= 1) {
    if (tid < s) {
      float ov = rr[tid + s]; int oi = ri[tid + s];
      if (ov > rr[tid] || (ov == rr[tid] && oi < ri[tid])) { rr[tid] = ov; ri[tid] = oi; }
    }
    __syncthreads();
  }
  __shared__ int slast;
  if (tid == 0) {
    if (rr[0] >= 0.f) {
      u64 pk = ((u64)f2key(rr[0]) << 32) | (u64)(0xFFFFFFFFu - (u32)ri[0]);
      atomicMax(&rpack[row], pk);
    }
    __threadfence();  // release: my g1p exchanges + rpack max before arrival
    u32 arr = atomicAdd(&rdone[row], 1u);
    slast = (arr == (u32)(SEGM - 1)) ? 1 : 0;
  }
  __syncthreads();
  if (!slast) return;
  __threadfence();  // acquire side

  // ---- last arriver: finish on gathered set (loads via device atomics) ----
  __shared__ u32 cnt1[1024]; __shared__ u64 fx1[1024];   // 12KB
  __shared__ u32 csuf[1024]; __shared__ u64 esuf[1024];  // 12KB
  __shared__ float subv[SUBC]; __shared__ int subi[SUBC];
  __shared__ float ssv[SUBC]; __shared__ int ssi[SUBC];  // 8KB
  __shared__ int eqs[EQC];
  __shared__ int scross, sfb, sca1, sns, seqn;
  __shared__ float sea1; __shared__ u32 svstar;

  int nf = (int)atomicAdd(&gcnt[slot], 0u);
  if (nf > GB1) nf = GB1;
  cnt1[tid] = 0; fx1[tid] = 0ull;
  if (tid == 0) { sns = 0; scross = -1; sfb = 0x7FFFFFFF; }
  __syncthreads();
  for (int i = tid; i < nf; i += TBB) {
    u64 p = atomicAdd(&g1p[gbase + i], 0ull);
    float x = __uint_as_float((u32)(p >> 32));
    u32 b = (f2key(x) >> 10) & 0x3FFu;
    float e = expf(x - m);
    atomicAdd(&cnt1[b], 1u);
    u64 fx = (u64)(e * FXS);
    if (fx) atomicAdd(&fx1[b], fx);
  }
  __syncthreads();
  csuf[tid] = cnt1[tid]; esuf[tid] = fx1[tid];
  __syncthreads();
  for (int stp = 1; stp < 1024; stp <<= 1) {
    u32 ca_ = 0; u64 ea_ = 0ull;
    if (tid + stp < 1024) { ca_ = csuf[tid + stp]; ea_ = esuf[tid + stp]; }
    __syncthreads();
    csuf[tid] += ca_; esuf[tid] += ea_;
    __syncthreads();
  }
  {
    u32 c = cnt1[tid];
    if (c) {
      float racc = (float)(esuf[tid] - fx1[tid]) * FXI;  // exact suffix above bin
      float ebv = (float)fx1[tid] * FXI;
      if (sea + (racc + ebv) >= target) atomicMax(&scross, tid);
      atomicMin(&sfb, tid);
    }
  }
  __syncthreads();
  if (tid == 0) {
    int cb = scross;
    if (cb < 0) cb = (sfb != 0x7FFFFFFF) ? sfb : 0;
    u32 cAbove = csuf[cb] - cnt1[cb];
    float eAbove = (float)(esuf[cb] - fx1[cb]) * FXI;
    scross = cb;
    sea1 = sea + eAbove;
    sca1 = sca + (int)cAbove;
  }
  __syncthreads();
  const u32 cb = (u32)scross;
  for (int i = tid; i < nf; i += TBB) {
    u64 p = atomicAdd(&g1p[gbase + i], 0ull);
    float x = __uint_as_float((u32)(p >> 32));
    if (((f2key(x) >> 10) & 0x3FFu) == cb) {
      int s2 = atomicAdd(&sns, 1);
      if (s2 < SUBC) { subv[s2] = x; subi[s2] = (int)(u32)(p & 0xFFFFFFFFull); }
    }
  }
  __syncthreads();
  int ns = sns; if (ns > SUBC) ns = SUBC;
  for (int i = tid; i < ns; i += TBB) {
    float v = subv[i]; int ix = subi[i];
    int rank = 0;
    for (int j2 = 0; j2 < ns; ++j2) {
      float vj = subv[j2]; int ij = subi[j2];
      if (vj > v || (vj == v && ij < ix)) rank++;
    }
    ssv[rank] = v; ssi[rank] = ix;
  }
  __syncthreads();
  if (tid == 0) {
    const float p = topps[row];
    float run_n = sea1 / S;
    const int have_above = (sca1 > 0);
    u32 lastkey = 0u; int lastr = 0, laststart = -1, anykept = 0;
    u32 vsel = 0u; int rsel = -1, bstart = 0;
    int j = 0;
    while (j < ns) {
      u32 key = f2key(ssv[j]);
      int c = 1;
      while (j + c < ns && f2key(ssv[j + c]) == key) ++c;
      float e = expf(ssv[j] - m);
      float en = e / S;
      int kept = 0;
      for (int q = 0; q < c; ++q) {
        float nn = run_n + en;
        if (nn < p) { run_n = nn; kept++; } else break;
      }
      if (kept == c) { lastkey = key; lastr = c; laststart = j; anykept = 1; j += c; continue; }
      if (kept > 0) { vsel = key; rsel = kept; bstart = j; }
      else if (anykept) { vsel = lastkey; rsel = lastr; bstart = laststart; }
      else if (have_above) { vsel = key; rsel = 0; bstart = j; }
      else { vsel = key; rsel = 1; bstart = j; }
      break;
    }
    if (rsel < 0) {
      if (anykept) { vsel = lastkey; rsel = lastr; bstart = laststart; }
      else if (ns > 0) {
        vsel = f2key(ssv[0]); bstart = 0;
        rsel = have_above ? 0 : 1;
      } else { vsel = 0u; rsel = 0; bstart = 0; }
    }
    int eqn = rsel;
    if (eqn > EQC) eqn = EQC;
    if (eqn < 0) eqn = 0;
    if (bstart + eqn > ns) eqn = ns - bstart;
    if (eqn < 0) eqn = 0;
    for (int q2 = 0; q2 < eqn; ++q2) eqs[q2] = ssi[bstart + q2];
    seqn = eqn; svstar = vsel;
  }
  __syncthreads();

  // boundary race over the gathered (bin==pfx) set
  const u32 vk = svstar;
  const int eqn = seqn;
  best = -1.f; bidx = 0x7FFFFFFF;
  for (int i = tid; i < nf; i += TBB) {
    u64 p = atomicAdd(&g1p[gbase + i], 0ull);
    float x = __uint_as_float((u32)(p >> 32));
    int ix = (int)(u32)(p & 0xFFFFFFFFull);
    u32 key = f2key(x);
    bool kept = key > vk;
    if (!kept && key == vk) {
      for (int e = 0; e < eqn; ++e) if (eqs[e] == ix) { kept = true; break; }
    }
    if (kept) {
      float q = fmaxf(-logf(ur[ix]), 1e-10f);
      float rt = expf(x - m) / q;
      if (rt > best || (rt == best && ix < bidx)) { best = rt; bidx = ix; }
    }
  }
  rr[tid] = best; ri[tid] = bidx;
  __syncthreads();
  for (int s = TBB >> 1; s > 0; s >>= 1) {
    if (tid < s) {
      float ov = rr[tid + s]; int oi = ri[tid + s];
      if (ov > rr[tid] || (ov == rr[tid] && oi < ri[tid])) { rr[tid] = ov; ri[tid] = oi; }
    }
    __syncthreads();
  }
  if (tid == 0) {
    u64 myPk = 0ull;
    if (rr[0] >= 0.f)
      myPk = ((u64)f2key(rr[0]) << 32) | (u64)(0xFFFFFFFFu - (u32)ri[0]);
    u64 prev = atomicMax(&rpack[row], myPk);
    u64 fin = prev > myPk ? prev : myPk;
    out[row] = (int)(0xFFFFFFFFu - (u32)(fin & 0xFFFFFFFFull));
  }
}

// kH: mode-0 finisher, unchanged R3-proven body.
__global__ __launch_bounds__(TBB) void kH(const float* __restrict__ topps,
                                          const float* __restrict__ noise,
                                          const int* __restrict__ topks,
                                          const float* __restrict__ maxpart,
                                          const u32* __restrict__ scnt,
                                          const float* __restrict__ candv,
                                          const int* __restrict__ candi,
                                          int* __restrict__ out, int V) {
  const int row = blockIdx.x, tid = threadIdx.x;
  const int kR = topks[row];
  if (!is_mode0(kR, V)) return;
  __shared__ float gv[GTOT]; __shared__ int gi[GTOT];
  __shared__ float sv[CAPSEG]; __shared__ int si[CAPSEG];
  __shared__ float fv[CAPSEG]; __shared__ int fi[CAPSEG];
  __shared__ float pe[CAPSEG];
  __shared__ float rr[TBB]; __shared__ int ri[TBB];
  __shared__ int offs[SA + 1];
  __shared__ u32 dh[256]; __shared__ u32 dsufx[256];
  __shared__ u32 sPrefix; __shared__ int sRemain, sNf, sDig;
  __shared__ int sJ; __shared__ float sZ2;
  if (tid == 0) {
    int o = 0;
    for (int s = 0; s < SA; ++s) {
      offs[s] = o;
      int c = (int)scnt[row * SA + s];
      if (c > CAPSEG) c = CAPSEG;
      if (c < 0) c = 0;
      o += c;
    }
    offs[SA] = o;
  }
  __syncthreads();
  const int g = offs[SA];
  for (int s = 0; s < SA; ++s) {
    const int o = offs[s], c = offs[s + 1] - o;
    const size_t cbase = ((size_t)row * SA + s) * CAPSEG;
    for (int i = tid; i < c; i += TBB) { gv[o + i] = candv[cbase + i]; gi[o + i] = candi[cbase + i]; }
  }
  __syncthreads();
  int kk = kR; if (kk > 256) kk = 256; if (kk > g) kk = g;
  if (tid == 0) { sPrefix = 0u; sRemain = (kk < 1) ? 1 : kk; }
  __syncthreads();
  for (int pass = 0; pass < 4; ++pass) {
    const int shift = 24 - 8 * pass;
    if (tid < 256) dh[tid] = 0;
    if (tid == 0) sDig = -1;
    __syncthreads();
    const u32 pref = sPrefix;
    for (int i = tid; i < g; i += TBB) {
      u32 key = f2key(gv[i]);
      if (pass == 0 || (key >> (shift + 8)) == pref)
        atomicAdd(&dh[(key >> shift) & 0xFFu], 1u);
    }
    __syncthreads();
    if (tid < 256) dsufx[tid] = dh[tid];
    __syncthreads();
    for (int stp = 1; stp < 256; stp <<= 1) {
      u32 addv = 0;
      if (tid < 256 && tid + stp < 256) addv = dsufx[tid + stp];
      __syncthreads();
      if (tid < 256) dsufx[tid] += addv;
      __syncthreads();
    }
    if (tid < 256) {
      u32 excl = dsufx[tid] - dh[tid];
      u32 rem = (u32)sRemain;
      if (dh[tid] && excl < rem && excl + dh[tid] >= rem) sDig = tid;  // unique
    }
    __syncthreads();
    if (tid == 0) {
      int d = sDig; if (d < 0) d = 0;
      u32 excl = dsufx[d] - dh[d];
      sRemain -= (int)excl;
      sPrefix = (sPrefix << 8) | (u32)d;
      if (pass == 3) sNf = 0;
    }
    __syncthreads();
  }
  const u32 Tk = sPrefix;
  for (int i = tid; i < g; i += TBB) {
    if (f2key(gv[i]) >= Tk) {
      int s = atomicAdd(&sNf, 1);
      if (s < CAPSEG) { fv[s] = gv[i]; fi[s] = gi[i]; }
    }
  }
  __syncthreads();
  int nf = sNf; if (nf > CAPSEG) nf = CAPSEG;
  for (int i = tid; i < nf; i += TBB) {
    float v = fv[i]; int ix = fi[i];
    int rank = 0;
    for (int j = 0; j < nf; ++j) {
      float vj = fv[j]; int ij = fi[j];
      if (vj > v || (vj == v && ij < ix)) rank++;
    }
    sv[rank] = v; si[rank] = ix;
  }
  __syncthreads();
  const float m = row_max(maxpart, row);
  const float p = topps[row];
  int keff = kR; if (keff > nf) keff = nf;
  for (int j = tid; j < keff; j += TBB) pe[j] = expf(sv[j] - m);
  __syncthreads();
  if (tid == 0) {
    int J = 1; float Z2 = 1.f;
    if (nf > 0 && keff > 0) {
      float Zk = 0.f;
      for (int j = 0; j < keff; ++j) Zk += pe[j];
      float c = 0.f; int Jc = 0;
      for (int j = 0; j < keff; ++j) {  // no break: cumsum non-decreasing
        float pr = pe[j] / Zk;
        c += pr;
        if (c < p) Jc++;
      }
      if (Jc < 1) Jc = 1;
      J = Jc;
      Z2 = 0.f;
      for (int j = 0; j < J && j < keff; ++j) Z2 += pe[j];
    }
    sJ = J; sZ2 = Z2;
  }
  __syncthreads();
  const int J = sJ; const float Z2 = sZ2;
  float best = -1.f; int bidx = 0x7FFFFFFF;
  for (int j = tid; j < J && j < nf; j += TBB) {
    int ix = si[j];
    float u = noise[(size_t)row * V + ix];
    float q = fmaxf(-logf(u), 1e-10f);
    float pr = pe[j] / Z2;
    float rt = pr / q;
    if (rt > best || (rt == best && ix < bidx)) { best = rt; bidx = ix; }
  }
  rr[tid] = best; ri[tid] = bidx;
  __syncthreads();
  for (int s = TBB >> 1; s > 0; s >>= 1) {
    if (tid < s) {
      float ov = rr[tid + s]; int oi = ri[tid + s];
      if (ov > rr[tid] || (ov == rr[tid] && oi < ri[tid])) { rr[tid] = ov; ri[tid] = oi; }
    }
    __syncthreads();
  }
  if (tid == 0) out[row] = (nf > 0) ? ri[0] : 0;
}

extern "C" void kernel_launch(void* const* d_in, const int* in_sizes, int n_in,
                              void* d_out, int out_size, void* d_ws, size_t ws_size,
                              hipStream_t stream) {
  const float* logits = (const float*)d_in[0];
  const float* temps = (const float*)d_in[1];
  const int* topks = (const int*)d_in[2];
  const float* topps = (const float*)d_in[3];
  const float* noise = (const float*)d_in[4];
  int* out = (int*)d_out;
  const int B = in_sizes[1];
  const int V = in_sizes[0] / B;
  (void)n_in; (void)out_size; (void)ws_size;

  u32* w = (u32*)d_ws;
  size_t o = 0;
  float* maxpart = (float*)(w + o); o += (size_t)B * SA;
  u32* scnt = w + o; o += (size_t)B * SA;
  float* candv = (float*)(w + o); o += (size_t)B * SA * CAPSEG;
  int* candi = (int*)(w + o); o += (size_t)B * SA * CAPSEG;
  if (o & 1) o += 1;
  const size_t zbase = o;                      // zeroed by kA (grid-stride)
  u64* m1e0 = (u64*)(w + o); o += 2 * (size_t)MAXM1 * NB;
  u32* m1c0 = w + o; o += (size_t)MAXM1 * NB;
  u64* rpack = (u64*)(w + o); o += 2 * (size_t)B;
  u32* rdone = w + o; o += (size_t)B;
  u32* gcnt = w + o; o += MAXM1;
  if (o & 1) o += 1;
  const size_t zwords = o - zbase;
  float* Sparts = (float*)(w + o); o += (size_t)MAXM1 * SEGE;
  if (o & 1) o += 1;
  u64* g1p = (u64*)(w + o); o += 2 * (size_t)MAXM1 * GB1;

  kA<<<dim3(B, SA), TAA, 0, stream>>>(logits, temps, topks, maxpart, scnt,
                                      candv, candi, w + zbase, zwords, V);
  kE<<<dim3(B, SEGE), TE, 0, stream>>>(logits, temps, topks, maxpart, Sparts, m1c0, m1e0, V);
  kM1<<<dim3(B, SEGM), TBB, 0, stream>>>(logits, temps, topks, topps, noise, maxpart,
                                         Sparts, m1c0, m1e0, g1p, gcnt, rpack, rdone, out, V);
  kH<<<B, TBB, 0, stream>>>(topps, noise, topks, maxpart, scnt, candv, candi, out, V);
}

// Round 7
// 223.853 us; speedup vs baseline: 1.3802x; 1.3802x over previous
//
#include <hip/hip_runtime.h>
#include <math.h>

#define SA 8      /* segments for kA */
#define SEGE 8    /* segments for kEH's kE role */
#define SEGM 8    /* segments for kM1 (R3-proven) */
#define NB 4096
#define TAA 512   /* kA threads */
#define HS 256    /* kA histogram-scan owner threads */
#define TBB 1024  /* kEH / kM1 threads */
#define SCT 256   /* scan threads (R3-proven chunk structure) */
#define CH (NB / SCT) /* 16 */
#define CAPSEG 512
#define GTOT (SA * CAPSEG) /* 4096 */
#define MAXM1 16
#define GB1 16384 /* gathered crossing-bin cap per mode-1 row */
#define SUBC 512  /* sub-bin cap */
#define EQC 64
#define FXS 1099511627776.0f /* 2^40 */
#define FXI (1.0f / 1099511627776.0f)

typedef unsigned u32;
typedef unsigned long long u64;

struct ScanSh {
  u32 axc[SCT]; float axe[SCT];
  u32 sufc[SCT]; float sufe[SCT];
  int cbin[SCT]; u32 cca[SCT]; float cea[SCT];
  int fbin[SCT]; u32 fca[SCT]; float fea[SCT];
};

__device__ __forceinline__ u32 f2key(float f) {
  u32 u = __float_as_uint(f);
  return u ^ ((u >> 31) ? 0xFFFFFFFFu : 0x80000000u);
}
__device__ __forceinline__ int is_mode0(int k, int V) {
  return (k >= 1 && k <= 256 && k < V);
}

__device__ __forceinline__ float row_max(const float* maxpart, int row) {
  float mm = maxpart[row * SA];
  for (int j = 1; j < SA; ++j) mm = fmaxf(mm, maxpart[row * SA + j]);
  return mm;
}

// Deterministic "slot-th mode-1 row" lookup: every block computes the same
// mapping from topks (flags to LDS in parallel, one tiny serial scan).
// Returns -1 if slot >= number of mode-1 rows.
__device__ int find_m1row(const int* topks, int B, int V, int slot, int tid,
                          int* flg, int* outrow) {
  for (int r = tid; r < B; r += blockDim.x) flg[r] = !is_mode0(topks[r], V);
  __syncthreads();
  if (tid == 0) {
    int c = 0, rsel = -1;
    for (int r = 0; r < B; ++r)
      if (flg[r]) { if (c == slot) rsel = r; ++c; }
    *outrow = rsel;
  }
  __syncthreads();
  return *outrow;
}

// R3-proven level-0 crossing scan, 256-owner structure.
__device__ void scan_level(const u32* cnt, const u64* e0, ScanSh* ax,
                           u32* sprefix, int* scnt_above, float* sexp_above,
                           float target, int tid) {
  if (tid < SCT) {
    u32 cc = 0; float ce = 0.f; const int base = tid * CH;
    for (int j = 0; j < CH; ++j) { cc += cnt[base + j]; ce += (float)e0[base + j] * FXI; }
    ax->axc[tid] = cc; ax->axe[tid] = ce;
  }
  __syncthreads();
  if (tid == 0) {
    u32 rc = 0; float re = 0.f;
    for (int c = SCT - 1; c >= 0; --c) {
      ax->sufc[c] = rc; ax->sufe[c] = re;
      rc += ax->axc[c]; re += ax->axe[c];
    }
  }
  __syncthreads();
  if (tid < SCT) {
    const int base = tid * CH;
    u32 rc = ax->sufc[tid]; float re = ax->sufe[tid];
    int best = -1; u32 bca = 0; float bea = 0.f;
    int fb = -1; u32 ffca = 0; float ffea = 0.f;
    for (int b = base + CH - 1; b >= base; --b) {
      u32 c = cnt[b]; float ebv = (float)e0[b] * FXI;
      bool cross = (c > 0) && ((re + ebv) >= target);
      if (cross && best < 0) { best = b; bca = rc; bea = re; }
      if (c > 0) { fb = b; ffca = rc; ffea = re; }
      rc += c; re += ebv;
    }
    ax->cbin[tid] = best; ax->cca[tid] = bca; ax->cea[tid] = bea;
    ax->fbin[tid] = fb; ax->fca[tid] = ffca; ax->fea[tid] = ffea;
  }
  __syncthreads();
  if (tid == 0) {
    int bsel = -1; u32 ca = 0; float ea = 0.f;
    for (int c = 0; c < SCT; ++c) {
      int b = ax->cbin[c];
      if (b > bsel) { bsel = b; ca = ax->cca[c]; ea = ax->cea[c]; }
    }
    if (bsel < 0) {
      for (int c = 0; c < SCT; ++c) {
        int b = ax->fbin[c];
        if (b >= 0 && (bsel < 0 || b < bsel)) { bsel = b; ca = ax->fca[c]; ea = ax->fea[c]; }
      }
    }
    if (bsel < 0) bsel = 0;
    *sprefix = (u32)bsel;
    *scnt_above = (int)ca;
    *sexp_above = ea;
  }
  __syncthreads();
}

// kA: RAW-KEY version (R6-proven). f2key(v/t) is monotone in v (t>0), so
// histogram/threshold/candidate predicate run on raw f2key(v) — no divides in
// hot loops; exact v/t stored only on acceptance. Seg max via max(v)/t.
// Also zero-fills the mode-1 accumulators (replaces memset dispatch).
__global__ __launch_bounds__(TAA) void kA(const float* __restrict__ logits,
                                          const float* __restrict__ temps,
                                          const int* __restrict__ topks,
                                          float* __restrict__ maxpart,
                                          u32* __restrict__ scnt,
                                          float* __restrict__ candv,
                                          int* __restrict__ candi,
                                          u32* __restrict__ zp, size_t zwords,
                                          int V) {
  const int row = blockIdx.x, seg = blockIdx.y, tid = threadIdx.x;
  __shared__ u32 cnt[NB];
  __shared__ float sm[TAA];
  __shared__ u32 cs[HS];
  __shared__ int bb[HS];
  __shared__ int lcnt;
  __shared__ u32 sT;
  {
    const size_t gid = ((size_t)blockIdx.y * gridDim.x + blockIdx.x) * TAA + tid;
    const size_t stride = (size_t)gridDim.x * gridDim.y * TAA;
    for (size_t i = gid; i < zwords; i += stride) zp[i] = 0;
  }
  const int k = topks[row];
  const int m0 = is_mode0(k, V);
  const float t = temps[row];
  const float* lr = logits + (size_t)row * V;
  const float4* l4 = (const float4*)lr;
  const int n4 = V >> 2;
  const int q0 = (int)((long long)seg * n4 / SA);
  const int q1 = (int)((long long)(seg + 1) * n4 / SA);
  float rmx = -INFINITY;  // raw-domain max
  if (m0) {
    for (int i = tid; i < NB; i += TAA) cnt[i] = 0;
    if (tid == 0) lcnt = 0;
    __syncthreads();
    for (int i = q0 + tid; i < q1; i += TAA) {
      float4 v = l4[i];
      rmx = fmaxf(rmx, fmaxf(fmaxf(v.x, v.y), fmaxf(v.z, v.w)));
      atomicAdd(&cnt[f2key(v.x) >> 20], 1u);
      atomicAdd(&cnt[f2key(v.y) >> 20], 1u);
      atomicAdd(&cnt[f2key(v.z) >> 20], 1u);
      atomicAdd(&cnt[f2key(v.w) >> 20], 1u);
    }
    if (seg == SA - 1)
      for (int i = (n4 << 2) + tid; i < V; i += TAA) {
        float x = lr[i];
        rmx = fmaxf(rmx, x);
        atomicAdd(&cnt[f2key(x) >> 20], 1u);
      }
  } else {
    for (int i = q0 + tid; i < q1; i += TAA) {
      float4 v = l4[i];
      rmx = fmaxf(rmx, fmaxf(fmaxf(v.x, v.y), fmaxf(v.z, v.w)));
    }
    if (seg == SA - 1)
      for (int i = (n4 << 2) + tid; i < V; i += TAA) rmx = fmaxf(rmx, lr[i]);
  }
  sm[tid] = rmx;
  __syncthreads();
  for (int s = TAA >> 1; s > 0; s >>= 1) {
    if (tid < s) sm[tid] = fmaxf(sm[tid], sm[tid + s]);
    __syncthreads();
  }
  if (tid == 0) maxpart[row * SA + seg] = sm[0] / t;  // exact: max(v)/t == max(v/t)
  if (!m0) return;
  if (tid < HS) {
    u32 cc = 0; const int base = tid * (NB / HS);
    for (int j = 0; j < NB / HS; ++j) cc += cnt[base + j];
    cs[tid] = cc;
  }
  __syncthreads();
  if (tid == 0) {
    u32 rc = 0;
    for (int c = HS - 1; c >= 0; --c) { u32 tmp = cs[c]; cs[c] = rc; rc += tmp; }
  }
  __syncthreads();
  const int kk = (k > 256) ? 256 : k;
  if (tid < HS) {
    const int base = tid * (NB / HS);
    u32 rc = cs[tid]; int best = -1;
    for (int b = base + NB / HS - 1; b >= base; --b) {
      u32 c = cnt[b];
      if (c && best < 0 && (int)(rc + c) >= kk) best = b;
      rc += c;
    }
    bb[tid] = best;
  }
  __syncthreads();
  if (tid == 0) {
    int bsel = -1;
    for (int c = 0; c < HS; ++c) if (bb[c] > bsel) bsel = bb[c];
    if (bsel < 0) { for (int b = 0; b < NB; ++b) if (cnt[b]) { bsel = b; break; } }
    if (bsel < 0) bsel = 0;
    sT = ((u32)bsel) << 20;
  }
  __syncthreads();
  const u32 T = sT;  // raw-domain threshold
  const size_t cbase = ((size_t)row * SA + seg) * CAPSEG;
  for (int i = q0 + tid; i < q1; i += TAA) {
    float4 v = l4[i];
    float vs[4] = {v.x, v.y, v.z, v.w};
#pragma unroll
    for (int j = 0; j < 4; ++j) {
      if (f2key(vs[j]) >= T) {
        int s = atomicAdd(&lcnt, 1);
        if (s < CAPSEG) { candv[cbase + s] = vs[j] / t; candi[cbase + s] = i * 4 + j; }
      }
    }
  }
  if (seg == SA - 1)
    for (int i = (n4 << 2) + tid; i < V; i += TAA) {
      float x = lr[i];
      if (f2key(x) >= T) {
        int s = atomicAdd(&lcnt, 1);
        if (s < CAPSEG) { candv[cbase + s] = x / t; candi[cbase + s] = i; }
      }
    }
  __syncthreads();
  if (tid == 0) { int n = lcnt; if (n > CAPSEG) n = CAPSEG; scnt[row * SA + seg] = (u32)n; }
}

// kEH: fused kH (mode-0 finisher, blocks [0,B)) + kE (mode-1 hist, blocks
// [B, B+MAXM1*SEGE)). The two roles touch disjoint rows and are independent;
// branch is uniform per block. Grid = 256 blocks = one resident wave.
__global__ __launch_bounds__(TBB) void kEH(const float* __restrict__ logits,
                                           const float* __restrict__ temps,
                                           const int* __restrict__ topks,
                                           const float* __restrict__ topps,
                                           const float* __restrict__ noise,
                                           const float* __restrict__ maxpart,
                                           const u32* __restrict__ scnt,
                                           const float* __restrict__ candv,
                                           const int* __restrict__ candi,
                                           float* __restrict__ Sparts,
                                           u32* __restrict__ m1c0,
                                           u64* __restrict__ m1e0,
                                           int* __restrict__ out, int B, int V) {
  const int bx = blockIdx.x, tid = threadIdx.x;
  // --- kH role LDS ---
  __shared__ float gv[GTOT]; __shared__ int gi[GTOT];
  __shared__ float sv[CAPSEG]; __shared__ int si[CAPSEG];
  __shared__ float fv[CAPSEG]; __shared__ int fi[CAPSEG];
  __shared__ float pe[CAPSEG];
  __shared__ float rr[TBB]; __shared__ int ri[TBB];
  __shared__ int offs[SA + 1];
  __shared__ u32 dh[256]; __shared__ u32 dsufx[256];
  __shared__ u32 sPrefix; __shared__ int sRemain, sNf, sDig;
  __shared__ int sJ; __shared__ float sZ2;
  // --- kE role LDS ---
  __shared__ u32 c0[NB];
  __shared__ u64 e0[NB];
  __shared__ float ss[TBB];
  __shared__ int flg[1024]; __shared__ int srow;

  if (bx >= B) {
    // ================= kE role =================
    const int e = bx - B;
    const int slot = e / SEGE, seg = e % SEGE;
    if (slot >= MAXM1) return;
    const int row = find_m1row(topks, B, V, slot, tid, flg, &srow);
    if (row < 0) return;
    for (int i = tid; i < NB; i += TBB) { c0[i] = 0; e0[i] = 0ull; }
    __syncthreads();
    const float t = temps[row];
    const float m = row_max(maxpart, row);
    const float* lr = logits + (size_t)row * V;
    const float4* l4 = (const float4*)lr;
    const int n4 = V >> 2;
    const int q0 = (int)((long long)seg * n4 / SEGE);
    const int q1 = (int)((long long)(seg + 1) * n4 / SEGE);
    float ls = 0.f;
    for (int i = q0 + tid; i < q1; i += TBB) {
      float4 v = l4[i];
      float xs[4] = {v.x / t, v.y / t, v.z / t, v.w / t};
#pragma unroll
      for (int j = 0; j < 4; ++j) {
        float ev = expf(xs[j] - m);
        ls += ev;
        u32 b = f2key(xs[j]) >> 20;
        atomicAdd(&c0[b], 1u);
        u64 fx = (u64)(ev * FXS);
        if (fx) atomicAdd(&e0[b], fx);
      }
    }
    if (seg == SEGE - 1)
      for (int i = (n4 << 2) + tid; i < V; i += TBB) {
        float x = lr[i] / t;
        float ev = expf(x - m);
        ls += ev;
        u32 b = f2key(x) >> 20;
        atomicAdd(&c0[b], 1u);
        u64 fx = (u64)(ev * FXS);
        if (fx) atomicAdd(&e0[b], fx);
      }
    ss[tid] = ls;
    __syncthreads();
    for (int s = TBB >> 1; s > 0; s >>= 1) {
      if (tid < s) ss[tid] += ss[tid + s];
      __syncthreads();
    }
    if (tid == 0) Sparts[slot * SEGE + seg] = ss[0];
    for (int b = tid; b < NB; b += TBB) {
      u32 c = c0[b]; if (c) atomicAdd(&m1c0[(size_t)slot * NB + b], c);
      u64 ev = e0[b]; if (ev) atomicAdd(&m1e0[(size_t)slot * NB + b], ev);
    }
    return;
  }

  // ================= kH role (R3-proven body, row = bx) =================
  const int row = bx;
  const int kR = topks[row];
  if (!is_mode0(kR, V)) return;
  if (tid == 0) {
    int o = 0;
    for (int s = 0; s < SA; ++s) {
      offs[s] = o;
      int c = (int)scnt[row * SA + s];
      if (c > CAPSEG) c = CAPSEG;
      if (c < 0) c = 0;
      o += c;
    }
    offs[SA] = o;
  }
  __syncthreads();
  const int g = offs[SA];
  for (int s = 0; s < SA; ++s) {
    const int o = offs[s], c = offs[s + 1] - o;
    const size_t cbase = ((size_t)row * SA + s) * CAPSEG;
    for (int i = tid; i < c; i += TBB) { gv[o + i] = candv[cbase + i]; gi[o + i] = candi[cbase + i]; }
  }
  __syncthreads();
  int kk = kR; if (kk > 256) kk = 256; if (kk > g) kk = g;
  if (tid == 0) { sPrefix = 0u; sRemain = (kk < 1) ? 1 : kk; }
  __syncthreads();
  for (int pass = 0; pass < 4; ++pass) {
    const int shift = 24 - 8 * pass;
    if (tid < 256) dh[tid] = 0;
    if (tid == 0) sDig = -1;
    __syncthreads();
    const u32 pref = sPrefix;
    for (int i = tid; i < g; i += TBB) {
      u32 key = f2key(gv[i]);
      if (pass == 0 || (key >> (shift + 8)) == pref)
        atomicAdd(&dh[(key >> shift) & 0xFFu], 1u);
    }
    __syncthreads();
    if (tid < 256) dsufx[tid] = dh[tid];
    __syncthreads();
    for (int stp = 1; stp < 256; stp <<= 1) {
      u32 addv = 0;
      if (tid < 256 && tid + stp < 256) addv = dsufx[tid + stp];
      __syncthreads();
      if (tid < 256) dsufx[tid] += addv;
      __syncthreads();
    }
    if (tid < 256) {
      u32 excl = dsufx[tid] - dh[tid];
      u32 rem = (u32)sRemain;
      if (dh[tid] && excl < rem && excl + dh[tid] >= rem) sDig = tid;  // unique
    }
    __syncthreads();
    if (tid == 0) {
      int d = sDig; if (d < 0) d = 0;
      u32 excl = dsufx[d] - dh[d];
      sRemain -= (int)excl;
      sPrefix = (sPrefix << 8) | (u32)d;
      if (pass == 3) sNf = 0;
    }
    __syncthreads();
  }
  const u32 Tk = sPrefix;
  for (int i = tid; i < g; i += TBB) {
    if (f2key(gv[i]) >= Tk) {
      int s = atomicAdd(&sNf, 1);
      if (s < CAPSEG) { fv[s] = gv[i]; fi[s] = gi[i]; }
    }
  }
  __syncthreads();
  int nf = sNf; if (nf > CAPSEG) nf = CAPSEG;
  for (int i = tid; i < nf; i += TBB) {
    float v = fv[i]; int ix = fi[i];
    int rank = 0;
    for (int j = 0; j < nf; ++j) {
      float vj = fv[j]; int ij = fi[j];
      if (vj > v || (vj == v && ij < ix)) rank++;
    }
    sv[rank] = v; si[rank] = ix;
  }
  __syncthreads();
  const float m = row_max(maxpart, row);
  const float p = topps[row];
  int keff = kR; if (keff > nf) keff = nf;
  for (int j = tid; j < keff; j += TBB) pe[j] = expf(sv[j] - m);
  __syncthreads();
  if (tid == 0) {
    int J = 1; float Z2 = 1.f;
    if (nf > 0 && keff > 0) {
      float Zk = 0.f;
      for (int j = 0; j < keff; ++j) Zk += pe[j];
      float c = 0.f; int Jc = 0;
      for (int j = 0; j < keff; ++j) {  // no break: cumsum non-decreasing
        float pr = pe[j] / Zk;
        c += pr;
        if (c < p) Jc++;
      }
      if (Jc < 1) Jc = 1;
      J = Jc;
      Z2 = 0.f;
      for (int j = 0; j < J && j < keff; ++j) Z2 += pe[j];
    }
    sJ = J; sZ2 = Z2;
  }
  __syncthreads();
  const int J = sJ; const float Z2 = sZ2;
  float best = -1.f; int bidx = 0x7FFFFFFF;
  for (int j = tid; j < J && j < nf; j += TBB) {
    int ix = si[j];
    float u = noise[(size_t)row * V + ix];
    float q = fmaxf(-logf(u), 1e-10f);
    float pr = pe[j] / Z2;
    float rt = pr / q;
    if (rt > best || (rt == best && ix < bidx)) { best = rt; bidx = ix; }
  }
  rr[tid] = best; ri[tid] = bidx;
  __syncthreads();
  for (int s = TBB >> 1; s > 0; s >>= 1) {
    if (tid < s) {
      float ov = rr[tid + s]; int oi = ri[tid + s];
      if (ov > rr[tid] || (ov == rr[tid] && oi < ri[tid])) { rr[tid] = ov; ri[tid] = oi; }
    }
    __syncthreads();
  }
  if (tid == 0) out[row] = (nf > 0) ? ri[0] : 0;
}

// kM1: mode-1 finish (R3-proven 43µs body), grid shrunk to MAXM1 x SEGM = 128
// blocks; slot = blockIdx.x, row found deterministically in-block. Each seg
// block: redundant LDS scan, gather its segment's crossing-bin elems (packed
// u64 atomicExch, tiny volume), race its segment's sure-kept (bin>pfx). Last
// arriver: sub-scan/sort/replay + boundary race, writes out[row].
__global__ __launch_bounds__(TBB) void kM1(const float* __restrict__ logits,
                                           const float* __restrict__ temps,
                                           const int* __restrict__ topks,
                                           const float* __restrict__ topps,
                                           const float* __restrict__ noise,
                                           const float* __restrict__ maxpart,
                                           const float* __restrict__ Sparts,
                                           const u32* __restrict__ m1c0,
                                           const u64* __restrict__ m1e0,
                                           u64* __restrict__ g1p,
                                           u32* __restrict__ gcnt,
                                           u64* __restrict__ rpack,
                                           u32* __restrict__ rdone,
                                           int* __restrict__ out, int B, int V) {
  const int slot = blockIdx.x, seg = blockIdx.y, tid = threadIdx.x;
  __shared__ int flg[1024]; __shared__ int srow;
  const int row = find_m1row(topks, B, V, slot, tid, flg, &srow);
  if (row < 0) return;

  __shared__ u32 cnt[NB];      // 16KB
  __shared__ u64 e0[NB];       // 32KB
  __shared__ ScanSh ax;        // 10KB
  __shared__ u32 spfx; __shared__ int sca; __shared__ float sea;
  __shared__ float rr[TBB]; __shared__ int ri[TBB];  // 8KB
  for (int i = tid; i < NB; i += TBB) {
    cnt[i] = m1c0[(size_t)slot * NB + i];
    e0[i] = m1e0[(size_t)slot * NB + i];
  }
  __syncthreads();
  float S = 0.f;
  for (int j = 0; j < SEGE; ++j) S += Sparts[slot * SEGE + j];
  const float target = topps[row] * S;
  scan_level(cnt, e0, &ax, &spfx, &sca, &sea, target, tid);
  const u32 pfx = spfx;

  const float t = temps[row];
  const float m = row_max(maxpart, row);
  const float* lr = logits + (size_t)row * V;
  const float* ur = noise + (size_t)row * V;
  const float4* l4 = (const float4*)lr;
  const float4* u4 = (const float4*)ur;
  const int n4 = V >> 2;
  const int q0 = (int)((long long)seg * n4 / SEGM);
  const int q1 = (int)((long long)(seg + 1) * n4 / SEGM);
  const size_t gbase = (size_t)slot * GB1;

  float best = -1.f; int bidx = 0x7FFFFFFF;
  for (int i = q0 + tid; i < q1; i += TBB) {
    float4 xv = l4[i];
    float4 uv = u4[i];
    float xs[4] = {xv.x / t, xv.y / t, xv.z / t, xv.w / t};
    float us[4] = {uv.x, uv.y, uv.z, uv.w};
#pragma unroll
    for (int j = 0; j < 4; ++j) {
      u32 key = f2key(xs[j]);
      u32 bin = key >> 20;
      int idx = i * 4 + j;
      if (bin == pfx) {
        u32 s2 = atomicAdd(&gcnt[slot], 1u);
        if (s2 < GB1)
          atomicExch(&g1p[gbase + s2],
                     ((u64)__float_as_uint(xs[j]) << 32) | (u64)(u32)idx);
      } else if (bin > pfx) {
        float q = fmaxf(-logf(us[j]), 1e-10f);
        float rt = expf(xs[j] - m) / q;
        if (rt > best || (rt == best && idx < bidx)) { best = rt; bidx = idx; }
      }
    }
  }
  if (seg == SEGM - 1)
    for (int i = (n4 << 2) + tid; i < V; i += TBB) {
      float x = lr[i] / t;
      u32 key = f2key(x);
      u32 bin = key >> 20;
      if (bin == pfx) {
        u32 s2 = atomicAdd(&gcnt[slot], 1u);
        if (s2 < GB1)
          atomicExch(&g1p[gbase + s2],
                     ((u64)__float_as_uint(x) << 32) | (u64)(u32)i);
      } else if (bin > pfx) {
        float q = fmaxf(-logf(ur[i]), 1e-10f);
        float rt = expf(x - m) / q;
        if (rt > best || (rt == best && i < bidx)) { best = rt; bidx = i; }
      }
    }
  rr[tid] = best; ri[tid] = bidx;
  __syncthreads();
  for (int s = TBB >> 1; s > 0; s >>= 1) {
    if (tid < s) {
      float ov = rr[tid + s]; int oi = ri[tid + s];
      if (ov > rr[tid] || (ov == rr[tid] && oi < ri[tid])) { rr[tid] = ov; ri[tid] = oi; }
    }
    __syncthreads();
  }
  __shared__ int slast;
  if (tid == 0) {
    if (rr[0] >= 0.f) {
      u64 pk = ((u64)f2key(rr[0]) << 32) | (u64)(0xFFFFFFFFu - (u32)ri[0]);
      atomicMax(&rpack[row], pk);
    }
    __threadfence();  // release: my g1p exchanges + rpack max before arrival
    u32 arr = atomicAdd(&rdone[row], 1u);
    slast = (arr == (u32)(SEGM - 1)) ? 1 : 0;
  }
  __syncthreads();
  if (!slast) return;
  __threadfence();  // acquire side

  // ---- last arriver: finish on gathered set (loads via device atomics) ----
  __shared__ u32 cnt1[1024]; __shared__ u64 fx1[1024];   // 12KB
  __shared__ u32 csuf[1024]; __shared__ u64 esuf[1024];  // 12KB
  __shared__ float subv[SUBC]; __shared__ int subi[SUBC];
  __shared__ float ssv[SUBC]; __shared__ int ssi[SUBC];  // 8KB
  __shared__ int eqs[EQC];
  __shared__ int scross, sfb, sca1, sns, seqn;
  __shared__ float sea1; __shared__ u32 svstar;

  int nf = (int)atomicAdd(&gcnt[slot], 0u);
  if (nf > GB1) nf = GB1;
  cnt1[tid] = 0; fx1[tid] = 0ull;
  if (tid == 0) { sns = 0; scross = -1; sfb = 0x7FFFFFFF; }
  __syncthreads();
  for (int i = tid; i < nf; i += TBB) {
    u64 p = atomicAdd(&g1p[gbase + i], 0ull);
    float x = __uint_as_float((u32)(p >> 32));
    u32 b = (f2key(x) >> 10) & 0x3FFu;
    float e = expf(x - m);
    atomicAdd(&cnt1[b], 1u);
    u64 fx = (u64)(e * FXS);
    if (fx) atomicAdd(&fx1[b], fx);
  }
  __syncthreads();
  csuf[tid] = cnt1[tid]; esuf[tid] = fx1[tid];
  __syncthreads();
  for (int stp = 1; stp < 1024; stp <<= 1) {
    u32 ca_ = 0; u64 ea_ = 0ull;
    if (tid + stp < 1024) { ca_ = csuf[tid + stp]; ea_ = esuf[tid + stp]; }
    __syncthreads();
    csuf[tid] += ca_; esuf[tid] += ea_;
    __syncthreads();
  }
  {
    u32 c = cnt1[tid];
    if (c) {
      float racc = (float)(esuf[tid] - fx1[tid]) * FXI;  // exact suffix above bin
      float ebv = (float)fx1[tid] * FXI;
      if (sea + (racc + ebv) >= target) atomicMax(&scross, tid);
      atomicMin(&sfb, tid);
    }
  }
  __syncthreads();
  if (tid == 0) {
    int cb = scross;
    if (cb < 0) cb = (sfb != 0x7FFFFFFF) ? sfb : 0;
    u32 cAbove = csuf[cb] - cnt1[cb];
    float eAbove = (float)(esuf[cb] - fx1[cb]) * FXI;
    scross = cb;
    sea1 = sea + eAbove;
    sca1 = sca + (int)cAbove;
  }
  __syncthreads();
  const u32 cb = (u32)scross;
  for (int i = tid; i < nf; i += TBB) {
    u64 p = atomicAdd(&g1p[gbase + i], 0ull);
    float x = __uint_as_float((u32)(p >> 32));
    if (((f2key(x) >> 10) & 0x3FFu) == cb) {
      int s2 = atomicAdd(&sns, 1);
      if (s2 < SUBC) { subv[s2] = x; subi[s2] = (int)(u32)(p & 0xFFFFFFFFull); }
    }
  }
  __syncthreads();
  int ns = sns; if (ns > SUBC) ns = SUBC;
  for (int i = tid; i < ns; i += TBB) {
    float v = subv[i]; int ix = subi[i];
    int rank = 0;
    for (int j2 = 0; j2 < ns; ++j2) {
      float vj = subv[j2]; int ij = subi[j2];
      if (vj > v || (vj == v && ij < ix)) rank++;
    }
    ssv[rank] = v; ssi[rank] = ix;
  }
  __syncthreads();
  if (tid == 0) {
    const float p = topps[row];
    float run_n = sea1 / S;
    const int have_above = (sca1 > 0);
    u32 lastkey = 0u; int lastr = 0, laststart = -1, anykept = 0;
    u32 vsel = 0u; int rsel = -1, bstart = 0;
    int j = 0;
    while (j < ns) {
      u32 key = f2key(ssv[j]);
      int c = 1;
      while (j + c < ns && f2key(ssv[j + c]) == key) ++c;
      float e = expf(ssv[j] - m);
      float en = e / S;
      int kept = 0;
      for (int q = 0; q < c; ++q) {
        float nn = run_n + en;
        if (nn < p) { run_n = nn; kept++; } else break;
      }
      if (kept == c) { lastkey = key; lastr = c; laststart = j; anykept = 1; j += c; continue; }
      if (kept > 0) { vsel = key; rsel = kept; bstart = j; }
      else if (anykept) { vsel = lastkey; rsel = lastr; bstart = laststart; }
      else if (have_above) { vsel = key; rsel = 0; bstart = j; }
      else { vsel = key; rsel = 1; bstart = j; }
      break;
    }
    if (rsel < 0) {
      if (anykept) { vsel = lastkey; rsel = lastr; bstart = laststart; }
      else if (ns > 0) {
        vsel = f2key(ssv[0]); bstart = 0;
        rsel = have_above ? 0 : 1;
      } else { vsel = 0u; rsel = 0; bstart = 0; }
    }
    int eqn = rsel;
    if (eqn > EQC) eqn = EQC;
    if (eqn < 0) eqn = 0;
    if (bstart + eqn > ns) eqn = ns - bstart;
    if (eqn < 0) eqn = 0;
    for (int q2 = 0; q2 < eqn; ++q2) eqs[q2] = ssi[bstart + q2];
    seqn = eqn; svstar = vsel;
  }
  __syncthreads();

  // boundary race over the gathered (bin==pfx) set
  const u32 vk = svstar;
  const int eqn = seqn;
  best = -1.f; bidx = 0x7FFFFFFF;
  for (int i = tid; i < nf; i += TBB) {
    u64 p = atomicAdd(&g1p[gbase + i], 0ull);
    float x = __uint_as_float((u32)(p >> 32));
    int ix = (int)(u32)(p & 0xFFFFFFFFull);
    u32 key = f2key(x);
    bool kept = key > vk;
    if (!kept && key == vk) {
      for (int e = 0; e < eqn; ++e) if (eqs[e] == ix) { kept = true; break; }
    }
    if (kept) {
      float q = fmaxf(-logf(ur[ix]), 1e-10f);
      float rt = expf(x - m) / q;
      if (rt > best || (rt == best && ix < bidx)) { best = rt; bidx = ix; }
    }
  }
  rr[tid] = best; ri[tid] = bidx;
  __syncthreads();
  for (int s = TBB >> 1; s > 0; s >>= 1) {
    if (tid < s) {
      float ov = rr[tid + s]; int oi = ri[tid + s];
      if (ov > rr[tid] || (ov == rr[tid] && oi < ri[tid])) { rr[tid] = ov; ri[tid] = oi; }
    }
    __syncthreads();
  }
  if (tid == 0) {
    u64 myPk = 0ull;
    if (rr[0] >= 0.f)
      myPk = ((u64)f2key(rr[0]) << 32) | (u64)(0xFFFFFFFFu - (u32)ri[0]);
    u64 prev = atomicMax(&rpack[row], myPk);
    u64 fin = prev > myPk ? prev : myPk;
    out[row] = (int)(0xFFFFFFFFu - (u32)(fin & 0xFFFFFFFFull));
  }
}

extern "C" void kernel_launch(void* const* d_in, const int* in_sizes, int n_in,
                              void* d_out, int out_size, void* d_ws, size_t ws_size,
                              hipStream_t stream) {
  const float* logits = (const float*)d_in[0];
  const float* temps = (const float*)d_in[1];
  const int* topks = (const int*)d_in[2];
  const float* topps = (const float*)d_in[3];
  const float* noise = (const float*)d_in[4];
  int* out = (int*)d_out;
  const int B = in_sizes[1];
  const int V = in_sizes[0] / B;
  (void)n_in; (void)out_size; (void)ws_size;

  u32* w = (u32*)d_ws;
  size_t o = 0;
  float* maxpart = (float*)(w + o); o += (size_t)B * SA;
  u32* scnt = w + o; o += (size_t)B * SA;
  float* candv = (float*)(w + o); o += (size_t)B * SA * CAPSEG;
  int* candi = (int*)(w + o); o += (size_t)B * SA * CAPSEG;
  if (o & 1) o += 1;
  const size_t zbase = o;                      // zeroed by kA (grid-stride)
  u64* m1e0 = (u64*)(w + o); o += 2 * (size_t)MAXM1 * NB;
  u32* m1c0 = w + o; o += (size_t)MAXM1 * NB;
  u64* rpack = (u64*)(w + o); o += 2 * (size_t)B;
  u32* rdone = w + o; o += (size_t)B;
  u32* gcnt = w + o; o += MAXM1;
  if (o & 1) o += 1;
  const size_t zwords = o - zbase;
  float* Sparts = (float*)(w + o); o += (size_t)MAXM1 * SEGE;
  if (o & 1) o += 1;
  u64* g1p = (u64*)(w + o); o += 2 * (size_t)MAXM1 * GB1;

  kA<<<dim3(B, SA), TAA, 0, stream>>>(logits, temps, topks, maxpart, scnt,
                                      candv, candi, w + zbase, zwords, V);
  kEH<<<B + MAXM1 * SEGE, TBB, 0, stream>>>(logits, temps, topks, topps, noise,
                                            maxpart, scnt, candv, candi,
                                            Sparts, m1c0, m1e0, out, B, V);
  kM1<<<dim3(MAXM1, SEGM), TBB, 0, stream>>>(logits, temps, topks, topps, noise,
                                             maxpart, Sparts, m1c0, m1e0, g1p,
                                             gcnt, rpack, rdone, out, B, V);
}

// Round 8
// 215.524 us; speedup vs baseline: 1.4335x; 1.0386x over previous
//
#include <hip/hip_runtime.h>
#include <math.h>

#define SA 8      /* segments for kA */
#define SEGE 8    /* segments for kEH's kE role */
#define SEGM 8    /* segments for kM1 gather */
#define NB 4096
#define TAA 512   /* kA threads */
#define HS 256    /* kA histogram-scan owner threads */
#define TBB 1024  /* kEH / kM1 threads */
#define SCT 256   /* scan threads (R3-proven chunk structure) */
#define CH (NB / SCT) /* 16 */
#define CAPSEG 512
#define GTOT (SA * CAPSEG) /* 4096 */
#define MAXM1 16
#define GB1 16384 /* gathered crossing-bin cap per mode-1 row */
#define SUBC 512  /* sub-bin cap */
#define EQC 64
#define FXS 1099511627776.0f /* 2^40 */
#define FXI (1.0f / 1099511627776.0f)

typedef unsigned u32;
typedef unsigned long long u64;

struct ScanSh {
  u32 axc[SCT]; float axe[SCT];
  u32 sufc[SCT]; float sufe[SCT];
  int cbin[SCT]; u32 cca[SCT]; float cea[SCT];
  int fbin[SCT]; u32 fca[SCT]; float fea[SCT];
};

struct Aux1 {
  u32 pfx;      // level-0 crossing bin
  int ca;       // cnt_above after level 0
  float ea;     // exp_above after level 0
  float S;
  float target; // p * S
};

__device__ __forceinline__ u32 f2key(float f) {
  u32 u = __float_as_uint(f);
  return u ^ ((u >> 31) ? 0xFFFFFFFFu : 0x80000000u);
}
__device__ __forceinline__ int is_mode0(int k, int V) {
  return (k >= 1 && k <= 256 && k < V);
}

__device__ __forceinline__ float row_max(const float* maxpart, int row) {
  float mm = maxpart[row * SA];
  for (int j = 1; j < SA; ++j) mm = fmaxf(mm, maxpart[row * SA + j]);
  return mm;
}

// Deterministic "slot-th mode-1 row" lookup (every block computes the same
// mapping from topks). Returns -1 if slot >= number of mode-1 rows.
__device__ int find_m1row(const int* topks, int B, int V, int slot, int tid,
                          int* flg, int* outrow) {
  for (int r = tid; r < B && r < 1024; r += blockDim.x) flg[r] = !is_mode0(topks[r], V);
  __syncthreads();
  if (tid == 0) {
    int c = 0, rsel = -1;
    for (int r = 0; r < B && r < 1024; ++r)
      if (flg[r]) { if (c == slot) rsel = r; ++c; }
    *outrow = rsel;
  }
  __syncthreads();
  return *outrow;
}

// R3-proven level-0 crossing scan, 256-owner structure.
__device__ void scan_level(const u32* cnt, const u64* e0, ScanSh* ax,
                           u32* sprefix, int* scnt_above, float* sexp_above,
                           float target, int tid) {
  if (tid < SCT) {
    u32 cc = 0; float ce = 0.f; const int base = tid * CH;
    for (int j = 0; j < CH; ++j) { cc += cnt[base + j]; ce += (float)e0[base + j] * FXI; }
    ax->axc[tid] = cc; ax->axe[tid] = ce;
  }
  __syncthreads();
  if (tid == 0) {
    u32 rc = 0; float re = 0.f;
    for (int c = SCT - 1; c >= 0; --c) {
      ax->sufc[c] = rc; ax->sufe[c] = re;
      rc += ax->axc[c]; re += ax->axe[c];
    }
  }
  __syncthreads();
  if (tid < SCT) {
    const int base = tid * CH;
    u32 rc = ax->sufc[tid]; float re = ax->sufe[tid];
    int best = -1; u32 bca = 0; float bea = 0.f;
    int fb = -1; u32 ffca = 0; float ffea = 0.f;
    for (int b = base + CH - 1; b >= base; --b) {
      u32 c = cnt[b]; float ebv = (float)e0[b] * FXI;
      bool cross = (c > 0) && ((re + ebv) >= target);
      if (cross && best < 0) { best = b; bca = rc; bea = re; }
      if (c > 0) { fb = b; ffca = rc; ffea = re; }
      rc += c; re += ebv;
    }
    ax->cbin[tid] = best; ax->cca[tid] = bca; ax->cea[tid] = bea;
    ax->fbin[tid] = fb; ax->fca[tid] = ffca; ax->fea[tid] = ffea;
  }
  __syncthreads();
  if (tid == 0) {
    int bsel = -1; u32 ca = 0; float ea = 0.f;
    for (int c = 0; c < SCT; ++c) {
      int b = ax->cbin[c];
      if (b > bsel) { bsel = b; ca = ax->cca[c]; ea = ax->cea[c]; }
    }
    if (bsel < 0) {
      for (int c = 0; c < SCT; ++c) {
        int b = ax->fbin[c];
        if (b >= 0 && (bsel < 0 || b < bsel)) { bsel = b; ca = ax->fca[c]; ea = ax->fea[c]; }
      }
    }
    if (bsel < 0) bsel = 0;
    *sprefix = (u32)bsel;
    *scnt_above = (int)ca;
    *sexp_above = ea;
  }
  __syncthreads();
}

// kA: RAW-KEY version (R6/R7-proven). No divides in hot loops; exact v/t
// stored only on acceptance. Also zero-fills mode-1 accumulators.
__global__ __launch_bounds__(TAA) void kA(const float* __restrict__ logits,
                                          const float* __restrict__ temps,
                                          const int* __restrict__ topks,
                                          float* __restrict__ maxpart,
                                          u32* __restrict__ scnt,
                                          float* __restrict__ candv,
                                          int* __restrict__ candi,
                                          u32* __restrict__ zp, size_t zwords,
                                          int V) {
  const int row = blockIdx.x, seg = blockIdx.y, tid = threadIdx.x;
  __shared__ u32 cnt[NB];
  __shared__ float sm[TAA];
  __shared__ u32 cs[HS];
  __shared__ int bb[HS];
  __shared__ int lcnt;
  __shared__ u32 sT;
  {
    const size_t gid = ((size_t)blockIdx.y * gridDim.x + blockIdx.x) * TAA + tid;
    const size_t stride = (size_t)gridDim.x * gridDim.y * TAA;
    for (size_t i = gid; i < zwords; i += stride) zp[i] = 0;
  }
  const int k = topks[row];
  const int m0 = is_mode0(k, V);
  const float t = temps[row];
  const float* lr = logits + (size_t)row * V;
  const float4* l4 = (const float4*)lr;
  const int n4 = V >> 2;
  const int q0 = (int)((long long)seg * n4 / SA);
  const int q1 = (int)((long long)(seg + 1) * n4 / SA);
  float rmx = -INFINITY;  // raw-domain max
  if (m0) {
    for (int i = tid; i < NB; i += TAA) cnt[i] = 0;
    if (tid == 0) lcnt = 0;
    __syncthreads();
    for (int i = q0 + tid; i < q1; i += TAA) {
      float4 v = l4[i];
      rmx = fmaxf(rmx, fmaxf(fmaxf(v.x, v.y), fmaxf(v.z, v.w)));
      atomicAdd(&cnt[f2key(v.x) >> 20], 1u);
      atomicAdd(&cnt[f2key(v.y) >> 20], 1u);
      atomicAdd(&cnt[f2key(v.z) >> 20], 1u);
      atomicAdd(&cnt[f2key(v.w) >> 20], 1u);
    }
    if (seg == SA - 1)
      for (int i = (n4 << 2) + tid; i < V; i += TAA) {
        float x = lr[i];
        rmx = fmaxf(rmx, x);
        atomicAdd(&cnt[f2key(x) >> 20], 1u);
      }
  } else {
    for (int i = q0 + tid; i < q1; i += TAA) {
      float4 v = l4[i];
      rmx = fmaxf(rmx, fmaxf(fmaxf(v.x, v.y), fmaxf(v.z, v.w)));
    }
    if (seg == SA - 1)
      for (int i = (n4 << 2) + tid; i < V; i += TAA) rmx = fmaxf(rmx, lr[i]);
  }
  sm[tid] = rmx;
  __syncthreads();
  for (int s = TAA >> 1; s > 0; s >>= 1) {
    if (tid < s) sm[tid] = fmaxf(sm[tid], sm[tid + s]);
    __syncthreads();
  }
  if (tid == 0) maxpart[row * SA + seg] = sm[0] / t;  // exact: max(v)/t == max(v/t)
  if (!m0) return;
  if (tid < HS) {
    u32 cc = 0; const int base = tid * (NB / HS);
    for (int j = 0; j < NB / HS; ++j) cc += cnt[base + j];
    cs[tid] = cc;
  }
  __syncthreads();
  if (tid == 0) {
    u32 rc = 0;
    for (int c = HS - 1; c >= 0; --c) { u32 tmp = cs[c]; cs[c] = rc; rc += tmp; }
  }
  __syncthreads();
  const int kk = (k > 256) ? 256 : k;
  if (tid < HS) {
    const int base = tid * (NB / HS);
    u32 rc = cs[tid]; int best = -1;
    for (int b = base + NB / HS - 1; b >= base; --b) {
      u32 c = cnt[b];
      if (c && best < 0 && (int)(rc + c) >= kk) best = b;
      rc += c;
    }
    bb[tid] = best;
  }
  __syncthreads();
  if (tid == 0) {
    int bsel = -1;
    for (int c = 0; c < HS; ++c) if (bb[c] > bsel) bsel = bb[c];
    if (bsel < 0) { for (int b = 0; b < NB; ++b) if (cnt[b]) { bsel = b; break; } }
    if (bsel < 0) bsel = 0;
    sT = ((u32)bsel) << 20;
  }
  __syncthreads();
  const u32 T = sT;  // raw-domain threshold
  const size_t cbase = ((size_t)row * SA + seg) * CAPSEG;
  for (int i = q0 + tid; i < q1; i += TAA) {
    float4 v = l4[i];
    float vs[4] = {v.x, v.y, v.z, v.w};
#pragma unroll
    for (int j = 0; j < 4; ++j) {
      if (f2key(vs[j]) >= T) {
        int s = atomicAdd(&lcnt, 1);
        if (s < CAPSEG) { candv[cbase + s] = vs[j] / t; candi[cbase + s] = i * 4 + j; }
      }
    }
  }
  if (seg == SA - 1)
    for (int i = (n4 << 2) + tid; i < V; i += TAA) {
      float x = lr[i];
      if (f2key(x) >= T) {
        int s = atomicAdd(&lcnt, 1);
        if (s < CAPSEG) { candv[cbase + s] = x / t; candi[cbase + s] = i; }
      }
    }
  __syncthreads();
  if (tid == 0) { int n = lcnt; if (n > CAPSEG) n = CAPSEG; scnt[row * SA + seg] = (u32)n; }
}

// kEH: fused kH (mode-0 finisher, blocks [0,B)) + kE-extended (mode-1, blocks
// [B, B+MAXM1*SEGE)). kE role now also computes per-bin packed winners of
// rt=exp(x-m)/q (LDS atomicMax -> global atomicMax; R5-proven mechanism) and
// the LAST ARRIVER per slot (rdoneE) reads back the summed hist, runs
// scan_level, and publishes {pfx,ca,ea,S,target} to aux (plain store —
// consumed across the kernel boundary by kM1).
__global__ __launch_bounds__(TBB) void kEH(const float* __restrict__ logits,
                                           const float* __restrict__ temps,
                                           const int* __restrict__ topks,
                                           const float* __restrict__ topps,
                                           const float* __restrict__ noise,
                                           const float* __restrict__ maxpart,
                                           const u32* __restrict__ scnt,
                                           const float* __restrict__ candv,
                                           const int* __restrict__ candi,
                                           float* __restrict__ Sparts,
                                           u32* __restrict__ m1c0,
                                           u64* __restrict__ m1e0,
                                           u64* __restrict__ m1w,
                                           u32* __restrict__ rdoneE,
                                           Aux1* __restrict__ aux,
                                           int* __restrict__ out, int B, int V) {
  const int bx = blockIdx.x, tid = threadIdx.x;
  // --- kH role LDS ---
  __shared__ float gv[GTOT]; __shared__ int gi[GTOT];
  __shared__ float sv[CAPSEG]; __shared__ int si[CAPSEG];
  __shared__ float fv[CAPSEG]; __shared__ int fi[CAPSEG];
  __shared__ float pe[CAPSEG];
  __shared__ float rr[TBB]; __shared__ int ri[TBB];
  __shared__ int offs[SA + 1];
  __shared__ u32 dh[256]; __shared__ u32 dsufx[256];
  __shared__ u32 sPrefix; __shared__ int sRemain, sNf, sDig;
  __shared__ int sJ; __shared__ float sZ2;
  // --- kE role LDS ---
  __shared__ u32 c0[NB];
  __shared__ u64 e0[NB];
  __shared__ u64 wtab[NB];
  __shared__ float ss[TBB];
  __shared__ ScanSh ax;
  __shared__ int flg[1024]; __shared__ int srow;
  __shared__ u32 spfx; __shared__ int sca; __shared__ float sea;
  __shared__ float sS; __shared__ int slast;

  if (bx >= B) {
    // ================= kE role =================
    const int e = bx - B;
    const int slot = e / SEGE, seg = e % SEGE;
    if (slot >= MAXM1) return;
    const int row = find_m1row(topks, B, V, slot, tid, flg, &srow);
    if (row < 0) return;
    for (int i = tid; i < NB; i += TBB) { c0[i] = 0; e0[i] = 0ull; wtab[i] = 0ull; }
    __syncthreads();
    const float t = temps[row];
    const float m = row_max(maxpart, row);
    const float* lr = logits + (size_t)row * V;
    const float* ur = noise + (size_t)row * V;
    const float4* l4 = (const float4*)lr;
    const float4* u4 = (const float4*)ur;
    const int n4 = V >> 2;
    const int q0 = (int)((long long)seg * n4 / SEGE);
    const int q1 = (int)((long long)(seg + 1) * n4 / SEGE);
    float ls = 0.f;
    for (int i = q0 + tid; i < q1; i += TBB) {
      float4 v = l4[i];
      float4 uv = u4[i];
      float xs[4] = {v.x / t, v.y / t, v.z / t, v.w / t};
      float us[4] = {uv.x, uv.y, uv.z, uv.w};
#pragma unroll
      for (int j = 0; j < 4; ++j) {
        float ev = expf(xs[j] - m);
        ls += ev;
        u32 b = f2key(xs[j]) >> 20;
        atomicAdd(&c0[b], 1u);
        u64 fx = (u64)(ev * FXS);
        if (fx) atomicAdd(&e0[b], fx);
        float q = fmaxf(-logf(us[j]), 1e-10f);
        float rt = ev / q;
        u64 wp = ((u64)f2key(rt) << 32) | (u64)(0xFFFFFFFFu - (u32)(i * 4 + j));
        atomicMax(&wtab[b], wp);
      }
    }
    if (seg == SEGE - 1)
      for (int i = (n4 << 2) + tid; i < V; i += TBB) {
        float x = lr[i] / t;
        float ev = expf(x - m);
        ls += ev;
        u32 b = f2key(x) >> 20;
        atomicAdd(&c0[b], 1u);
        u64 fx = (u64)(ev * FXS);
        if (fx) atomicAdd(&e0[b], fx);
        float q = fmaxf(-logf(ur[i]), 1e-10f);
        float rt = ev / q;
        u64 wp = ((u64)f2key(rt) << 32) | (u64)(0xFFFFFFFFu - (u32)i);
        atomicMax(&wtab[b], wp);
      }
    ss[tid] = ls;
    __syncthreads();
    for (int s = TBB >> 1; s > 0; s >>= 1) {
      if (tid < s) ss[tid] += ss[tid + s];
      __syncthreads();
    }
    if (tid == 0)
      atomicExch((u32*)&Sparts[slot * SEGE + seg], __float_as_uint(ss[0]));
    for (int b = tid; b < NB; b += TBB) {
      u32 c = c0[b]; if (c) atomicAdd(&m1c0[(size_t)slot * NB + b], c);
      u64 ev = e0[b]; if (ev) atomicAdd(&m1e0[(size_t)slot * NB + b], ev);
      u64 wv = wtab[b]; if (wv) atomicMax(&m1w[(size_t)slot * NB + b], wv);
    }
    __syncthreads();  // drains each thread's outstanding atomics (vmcnt 0)
    if (tid == 0) {
      __threadfence();  // release
      u32 arr = atomicAdd(&rdoneE[slot], 1u);
      slast = (arr == (u32)(SEGE - 1)) ? 1 : 0;
    }
    __syncthreads();
    if (!slast) return;
    __threadfence();  // acquire

    // ---- last arriver: readback summed hist, scan, publish Aux ----
    for (int i = tid; i < NB; i += TBB) {
      c0[i] = atomicAdd(&m1c0[(size_t)slot * NB + i], 0u);
      e0[i] = atomicAdd(&m1e0[(size_t)slot * NB + i], 0ull);
    }
    if (tid == 0) {
      float S = 0.f;
      for (int j = 0; j < SEGE; ++j)
        S += __uint_as_float(atomicAdd((u32*)&Sparts[slot * SEGE + j], 0u));
      sS = S;
    }
    __syncthreads();
    const float target = topps[row] * sS;
    scan_level(c0, e0, &ax, &spfx, &sca, &sea, target, tid);
    if (tid == 0) {
      Aux1 a; a.pfx = spfx; a.ca = sca; a.ea = sea; a.S = sS; a.target = target;
      aux[slot] = a;  // plain store; consumed after kernel boundary
    }
    return;
  }

  // ================= kH role (R3-proven body, row = bx) =================
  const int row = bx;
  const int kR = topks[row];
  if (!is_mode0(kR, V)) return;
  if (tid == 0) {
    int o = 0;
    for (int s = 0; s < SA; ++s) {
      offs[s] = o;
      int c = (int)scnt[row * SA + s];
      if (c > CAPSEG) c = CAPSEG;
      if (c < 0) c = 0;
      o += c;
    }
    offs[SA] = o;
  }
  __syncthreads();
  const int g = offs[SA];
  for (int s = 0; s < SA; ++s) {
    const int o = offs[s], c = offs[s + 1] - o;
    const size_t cbase = ((size_t)row * SA + s) * CAPSEG;
    for (int i = tid; i < c; i += TBB) { gv[o + i] = candv[cbase + i]; gi[o + i] = candi[cbase + i]; }
  }
  __syncthreads();
  int kk = kR; if (kk > 256) kk = 256; if (kk > g) kk = g;
  if (tid == 0) { sPrefix = 0u; sRemain = (kk < 1) ? 1 : kk; }
  __syncthreads();
  for (int pass = 0; pass < 4; ++pass) {
    const int shift = 24 - 8 * pass;
    if (tid < 256) dh[tid] = 0;
    if (tid == 0) sDig = -1;
    __syncthreads();
    const u32 pref = sPrefix;
    for (int i = tid; i < g; i += TBB) {
      u32 key = f2key(gv[i]);
      if (pass == 0 || (key >> (shift + 8)) == pref)
        atomicAdd(&dh[(key >> shift) & 0xFFu], 1u);
    }
    __syncthreads();
    if (tid < 256) dsufx[tid] = dh[tid];
    __syncthreads();
    for (int stp = 1; stp < 256; stp <<= 1) {
      u32 addv = 0;
      if (tid < 256 && tid + stp < 256) addv = dsufx[tid + stp];
      __syncthreads();
      if (tid < 256) dsufx[tid] += addv;
      __syncthreads();
    }
    if (tid < 256) {
      u32 excl = dsufx[tid] - dh[tid];
      u32 rem = (u32)sRemain;
      if (dh[tid] && excl < rem && excl + dh[tid] >= rem) sDig = tid;  // unique
    }
    __syncthreads();
    if (tid == 0) {
      int d = sDig; if (d < 0) d = 0;
      u32 excl = dsufx[d] - dh[d];
      sRemain -= (int)excl;
      sPrefix = (sPrefix << 8) | (u32)d;
      if (pass == 3) sNf = 0;
    }
    __syncthreads();
  }
  const u32 Tk = sPrefix;
  for (int i = tid; i < g; i += TBB) {
    if (f2key(gv[i]) >= Tk) {
      int s = atomicAdd(&sNf, 1);
      if (s < CAPSEG) { fv[s] = gv[i]; fi[s] = gi[i]; }
    }
  }
  __syncthreads();
  int nf = sNf; if (nf > CAPSEG) nf = CAPSEG;
  for (int i = tid; i < nf; i += TBB) {
    float v = fv[i]; int ix = fi[i];
    int rank = 0;
    for (int j = 0; j < nf; ++j) {
      float vj = fv[j]; int ij = fi[j];
      if (vj > v || (vj == v && ij < ix)) rank++;
    }
    sv[rank] = v; si[rank] = ix;
  }
  __syncthreads();
  const float m = row_max(maxpart, row);
  const float p = topps[row];
  int keff = kR; if (keff > nf) keff = nf;
  for (int j = tid; j < keff; j += TBB) pe[j] = expf(sv[j] - m);
  __syncthreads();
  if (tid == 0) {
    int J = 1; float Z2 = 1.f;
    if (nf > 0 && keff > 0) {
      float Zk = 0.f;
      for (int j = 0; j < keff; ++j) Zk += pe[j];
      float c = 0.f; int Jc = 0;
      for (int j = 0; j < keff; ++j) {  // no break: cumsum non-decreasing
        float pr = pe[j] / Zk;
        c += pr;
        if (c < p) Jc++;
      }
      if (Jc < 1) Jc = 1;
      J = Jc;
      Z2 = 0.f;
      for (int j = 0; j < J && j < keff; ++j) Z2 += pe[j];
    }
    sJ = J; sZ2 = Z2;
  }
  __syncthreads();
  const int J = sJ; const float Z2 = sZ2;
  float best = -1.f; int bidx = 0x7FFFFFFF;
  for (int j = tid; j < J && j < nf; j += TBB) {
    int ix = si[j];
    float u = noise[(size_t)row * V + ix];
    float q = fmaxf(-logf(u), 1e-10f);
    float pr = pe[j] / Z2;
    float rt = pr / q;
    if (rt > best || (rt == best && ix < bidx)) { best = rt; bidx = ix; }
  }
  rr[tid] = best; ri[tid] = bidx;
  __syncthreads();
  for (int s = TBB >> 1; s > 0; s >>= 1) {
    if (tid < s) {
      float ov = rr[tid + s]; int oi = ri[tid + s];
      if (ov > rr[tid] || (ov == rr[tid] && oi < ri[tid])) { rr[tid] = ov; ri[tid] = oi; }
    }
    __syncthreads();
  }
  if (tid == 0) out[row] = (nf > 0) ? ri[0] : 0;
}

// kM1: slim mode-1 finish. Grid MAXM1 x SEGM. Seg blocks: read Aux (kernel
// boundary, plain), gather pfx-bin elements from own logits segment (packed
// u64 atomicExch, ~31 hits), arrive. Last arriver: sub-scan/sort/replay on
// gathered set + boundary race + wtab (bins>pfx) max -> out[row]. No hist
// load, no scan, no noise read in the seg pass.
__global__ __launch_bounds__(TBB) void kM1(const float* __restrict__ logits,
                                           const float* __restrict__ temps,
                                           const int* __restrict__ topks,
                                           const float* __restrict__ topps,
                                           const float* __restrict__ noise,
                                           const float* __restrict__ maxpart,
                                           const Aux1* __restrict__ aux,
                                           const u64* __restrict__ m1w,
                                           u64* __restrict__ g1p,
                                           u32* __restrict__ gcnt,
                                           u32* __restrict__ rdoneM,
                                           int* __restrict__ out, int B, int V) {
  const int slot = blockIdx.x, seg = blockIdx.y, tid = threadIdx.x;
  __shared__ int flg[1024]; __shared__ int srow;
  const int row = find_m1row(topks, B, V, slot, tid, flg, &srow);
  if (row < 0) return;

  const Aux1 a = aux[slot];   // written by kEH (kernel boundary)
  const u32 pfx = a.pfx;
  const float t = temps[row];
  const float m = row_max(maxpart, row);
  const float* lr = logits + (size_t)row * V;
  const float* ur = noise + (size_t)row * V;
  const float4* l4 = (const float4*)lr;
  const int n4 = V >> 2;
  const int q0 = (int)((long long)seg * n4 / SEGM);
  const int q1 = (int)((long long)(seg + 1) * n4 / SEGM);
  const size_t gbase = (size_t)slot * GB1;

  for (int i = q0 + tid; i < q1; i += TBB) {
    float4 v = l4[i];
    float xs[4] = {v.x / t, v.y / t, v.z / t, v.w / t};
#pragma unroll
    for (int j = 0; j < 4; ++j) {
      if ((f2key(xs[j]) >> 20) == pfx) {
        u32 s2 = atomicAdd(&gcnt[slot], 1u);
        if (s2 < GB1)
          atomicExch(&g1p[gbase + s2],
                     ((u64)__float_as_uint(xs[j]) << 32) | (u64)(u32)(i * 4 + j));
      }
    }
  }
  if (seg == SEGM - 1)
    for (int i = (n4 << 2) + tid; i < V; i += TBB) {
      float x = lr[i] / t;
      if ((f2key(x) >> 20) == pfx) {
        u32 s2 = atomicAdd(&gcnt[slot], 1u);
        if (s2 < GB1)
          atomicExch(&g1p[gbase + s2],
                     ((u64)__float_as_uint(x) << 32) | (u64)(u32)i);
      }
    }
  __syncthreads();  // drains each thread's outstanding atomics
  __shared__ int slast;
  if (tid == 0) {
    __threadfence();  // release
    u32 arr = atomicAdd(&rdoneM[slot], 1u);
    slast = (arr == (u32)(SEGM - 1)) ? 1 : 0;
  }
  __syncthreads();
  if (!slast) return;
  __threadfence();  // acquire

  // ---- last arriver: finish on gathered set + wtab winners ----
  __shared__ u32 cnt1[1024]; __shared__ u64 fx1[1024];
  __shared__ u32 csuf[1024]; __shared__ u64 esuf[1024];
  __shared__ float subv[SUBC]; __shared__ int subi[SUBC];
  __shared__ float ssv[SUBC]; __shared__ int ssi[SUBC];
  __shared__ u64 rrp[TBB];
  __shared__ int eqs[EQC];
  __shared__ int scross, sfb, sca1, sns, seqn;
  __shared__ float sea1; __shared__ u32 svstar;

  int nf = (int)atomicAdd(&gcnt[slot], 0u);
  if (nf > GB1) nf = GB1;
  cnt1[tid] = 0; fx1[tid] = 0ull;
  if (tid == 0) { sns = 0; scross = -1; sfb = 0x7FFFFFFF; }
  __syncthreads();
  for (int i = tid; i < nf; i += TBB) {
    u64 p = atomicAdd(&g1p[gbase + i], 0ull);
    float x = __uint_as_float((u32)(p >> 32));
    u32 b = (f2key(x) >> 10) & 0x3FFu;
    float e = expf(x - m);
    atomicAdd(&cnt1[b], 1u);
    u64 fx = (u64)(e * FXS);
    if (fx) atomicAdd(&fx1[b], fx);
  }
  __syncthreads();
  csuf[tid] = cnt1[tid]; esuf[tid] = fx1[tid];
  __syncthreads();
  for (int stp = 1; stp < 1024; stp <<= 1) {
    u32 ca_ = 0; u64 ea_ = 0ull;
    if (tid + stp < 1024) { ca_ = csuf[tid + stp]; ea_ = esuf[tid + stp]; }
    __syncthreads();
    csuf[tid] += ca_; esuf[tid] += ea_;
    __syncthreads();
  }
  {
    u32 c = cnt1[tid];
    if (c) {
      float racc = (float)(esuf[tid] - fx1[tid]) * FXI;  // exact suffix above bin
      float ebv = (float)fx1[tid] * FXI;
      if (a.ea + (racc + ebv) >= a.target) atomicMax(&scross, tid);
      atomicMin(&sfb, tid);
    }
  }
  __syncthreads();
  if (tid == 0) {
    int cb = scross;
    if (cb < 0) cb = (sfb != 0x7FFFFFFF) ? sfb : 0;
    u32 cAbove = csuf[cb] - cnt1[cb];
    float eAbove = (float)(esuf[cb] - fx1[cb]) * FXI;
    scross = cb;
    sea1 = a.ea + eAbove;
    sca1 = a.ca + (int)cAbove;
  }
  __syncthreads();
  const u32 cb = (u32)scross;
  for (int i = tid; i < nf; i += TBB) {
    u64 p = atomicAdd(&g1p[gbase + i], 0ull);
    float x = __uint_as_float((u32)(p >> 32));
    if (((f2key(x) >> 10) & 0x3FFu) == cb) {
      int s2 = atomicAdd(&sns, 1);
      if (s2 < SUBC) { subv[s2] = x; subi[s2] = (int)(u32)(p & 0xFFFFFFFFull); }
    }
  }
  __syncthreads();
  int ns = sns; if (ns > SUBC) ns = SUBC;
  for (int i = tid; i < ns; i += TBB) {
    float v = subv[i]; int ix = subi[i];
    int rank = 0;
    for (int j2 = 0; j2 < ns; ++j2) {
      float vj = subv[j2]; int ij = subi[j2];
      if (vj > v || (vj == v && ij < ix)) rank++;
    }
    ssv[rank] = v; ssi[rank] = ix;
  }
  __syncthreads();
  if (tid == 0) {
    const float p = topps[row];
    float run_n = sea1 / a.S;
    const int have_above = (sca1 > 0);
    u32 lastkey = 0u; int lastr = 0, laststart = -1, anykept = 0;
    u32 vsel = 0u; int rsel = -1, bstart = 0;
    int j = 0;
    while (j < ns) {
      u32 key = f2key(ssv[j]);
      int c = 1;
      while (j + c < ns && f2key(ssv[j + c]) == key) ++c;
      float e = expf(ssv[j] - m);
      float en = e / a.S;
      int kept = 0;
      for (int q = 0; q < c; ++q) {
        float nn = run_n + en;
        if (nn < p) { run_n = nn; kept++; } else break;
      }
      if (kept == c) { lastkey = key; lastr = c; laststart = j; anykept = 1; j += c; continue; }
      if (kept > 0) { vsel = key; rsel = kept; bstart = j; }
      else if (anykept) { vsel = lastkey; rsel = lastr; bstart = laststart; }
      else if (have_above) { vsel = key; rsel = 0; bstart = j; }
      else { vsel = key; rsel = 1; bstart = j; }
      break;
    }
    if (rsel < 0) {
      if (anykept) { vsel = lastkey; rsel = lastr; bstart = laststart; }
      else if (ns > 0) {
        vsel = f2key(ssv[0]); bstart = 0;
        rsel = have_above ? 0 : 1;
      } else { vsel = 0u; rsel = 0; bstart = 0; }
    }
    int eqn = rsel;
    if (eqn > EQC) eqn = EQC;
    if (eqn < 0) eqn = 0;
    if (bstart + eqn > ns) eqn = ns - bstart;
    if (eqn < 0) eqn = 0;
    for (int q2 = 0; q2 < eqn; ++q2) eqs[q2] = ssi[bstart + q2];
    seqn = eqn; svstar = vsel;
  }
  __syncthreads();

  // winners above pfx (from wtab, written in kEH) + boundary race
  u64 best = 0ull;
  for (int b = (int)pfx + 1 + tid; b < NB; b += TBB) {
    u64 w = m1w[(size_t)slot * NB + b];  // prior kernel -> plain read OK
    if (w > best) best = w;
  }
  const u32 vk = svstar;
  const int eqn = seqn;
  for (int i = tid; i < nf; i += TBB) {
    u64 p = atomicAdd(&g1p[gbase + i], 0ull);
    float x = __uint_as_float((u32)(p >> 32));
    int ix = (int)(u32)(p & 0xFFFFFFFFull);
    u32 key = f2key(x);
    bool kept = key > vk;
    if (!kept && key == vk) {
      for (int e = 0; e < eqn; ++e) if (eqs[e] == ix) { kept = true; break; }
    }
    if (kept) {
      float q = fmaxf(-logf(ur[ix]), 1e-10f);
      float rt = expf(x - m) / q;
      u64 wp = ((u64)f2key(rt) << 32) | (u64)(0xFFFFFFFFu - (u32)ix);
      if (wp > best) best = wp;
    }
  }
  rrp[tid] = best;
  __syncthreads();
  for (int s = TBB >> 1; s > 0; s >>= 1) {
    if (tid < s) { if (rrp[tid + s] > rrp[tid]) rrp[tid] = rrp[tid + s]; }
    __syncthreads();
  }
  if (tid == 0)
    out[row] = (rrp[0] != 0ull) ? (int)(0xFFFFFFFFu - (u32)(rrp[0] & 0xFFFFFFFFull)) : 0;
}

extern "C" void kernel_launch(void* const* d_in, const int* in_sizes, int n_in,
                              void* d_out, int out_size, void* d_ws, size_t ws_size,
                              hipStream_t stream) {
  const float* logits = (const float*)d_in[0];
  const float* temps = (const float*)d_in[1];
  const int* topks = (const int*)d_in[2];
  const float* topps = (const float*)d_in[3];
  const float* noise = (const float*)d_in[4];
  int* out = (int*)d_out;
  const int B = in_sizes[1];
  const int V = in_sizes[0] / B;
  (void)n_in; (void)out_size; (void)ws_size;

  u32* w = (u32*)d_ws;
  size_t o = 0;
  float* maxpart = (float*)(w + o); o += (size_t)B * SA;
  u32* scnt = w + o; o += (size_t)B * SA;
  float* candv = (float*)(w + o); o += (size_t)B * SA * CAPSEG;
  int* candi = (int*)(w + o); o += (size_t)B * SA * CAPSEG;
  if (o & 1) o += 1;
  const size_t zbase = o;                      // zeroed by kA (grid-stride)
  u64* m1e0 = (u64*)(w + o); o += 2 * (size_t)MAXM1 * NB;
  u64* m1w = (u64*)(w + o); o += 2 * (size_t)MAXM1 * NB;
  u32* m1c0 = w + o; o += (size_t)MAXM1 * NB;
  u32* gcnt = w + o; o += MAXM1;
  u32* rdoneE = w + o; o += MAXM1;
  u32* rdoneM = w + o; o += MAXM1;
  if (o & 1) o += 1;
  const size_t zwords = o - zbase;
  float* Sparts = (float*)(w + o); o += (size_t)MAXM1 * SEGE;
  if (o & 1) o += 1;
  Aux1* aux = (Aux1*)(w + o); o += (sizeof(Aux1) / 4) * (size_t)MAXM1 + 4;
  if (o & 1) o += 1;
  u64* g1p = (u64*)(w + o); o += 2 * (size_t)MAXM1 * GB1;

  kA<<<dim3(B, SA), TAA, 0, stream>>>(logits, temps, topks, maxpart, scnt,
                                      candv, candi, w + zbase, zwords, V);
  kEH<<<B + MAXM1 * SEGE, TBB, 0, stream>>>(logits, temps, topks, topps, noise,
                                            maxpart, scnt, candv, candi,
                                            Sparts, m1c0, m1e0, m1w, rdoneE,
                                            aux, out, B, V);
  kM1<<<dim3(MAXM1, SEGM), TBB, 0, stream>>>(logits, temps, topks, topps, noise,
                                             maxpart, aux, m1w, g1p, gcnt,
                                             rdoneM, out, B, V);
}